// Round 2
// baseline (304.782 us; speedup 1.0000x reference)
//
#include <hip/hip_runtime.h>
#include <stdint.h>

// SpatialSelfAttention: B=4, C=512, P=4096, 32 groups.
// Pipeline (round 9: big tiles + XCD swizzle + atomic-free rsum):
//   1. cvt weights fp32->bf16 (wq,bq prescaled by 1.02014 = qscale2/2^-4)
//   2. gn_stats + gn_norm -> h_t [B*P, C] bf16 (LDS tile transpose)
//   3. qk8 = h_t @ [wq;wk]^T  [B*P, 1024] fp8 e4m3 (256-tile, 512 thr)
//      v_c = wv @ h_t^T       [C, B*P]  fp8 e4m3
//   4. P[b] = exp2(2^-4 * q8[b] @ k8[b]^T)  [P,P] fp8 via MX-scaled
//      mfma_scale_f32_16x16x128_f8f6f4 (A-scale e8m0=123 -> 2^-4).
//      256x128 tile, 512 thr (8 waves, MI=4/wave), 3 blocks/CU.
//      Row sums -> non-atomic partials part2[bz][64][P] (aliases dead h_t).
//   5. rsum_reduce: rsum[bz][r] = sum_64 part2  (~2us)
//   6. h_at[b] = (P[b] @ v_c[b]^T) / rsum  [P, C] bf16, 128x128 MX-fp8
//   7. out = wo @ h_at^T + bo + x  [C, B*P] fp32 == d_out layout
// QK/EXP/PV use bijective XCD swizzle (per-XCD L2 working set <= 4MB);
// V/OUT keep default mapping (already XCD-local: same-x blocks share B).
// Both GEMM templates generalized to NT=512 (8 waves): r0 in [0,NT/8),
// stage batches RB=NT/8 rows, wave tile WROWS=TM/(NW/2); the sigma/XOR
// invariant row&7 == l&7 is preserved for all NT/TM used here.

typedef __bf16 bf16_t;
typedef __attribute__((ext_vector_type(4))) __bf16 bf16x4;
typedef __attribute__((ext_vector_type(8))) __bf16 bf16x8;
typedef __attribute__((ext_vector_type(4))) float floatx4;
typedef __attribute__((ext_vector_type(8))) int intx8;

constexpr int CDIM = 512;
constexpr int PDIM = 4096;

__device__ __forceinline__ void ld_g2l(const void* g, void* l) {
  __builtin_amdgcn_global_load_lds(
      (const __attribute__((address_space(1))) void*)g,
      (__attribute__((address_space(3))) void*)l,
      16, 0, 0);
}

__device__ __forceinline__ uint32_t pk_fp8x4(float a, float b, float c,
                                             float d) {
  int r = __builtin_amdgcn_cvt_pk_fp8_f32(a, b, 0, false);
  r = __builtin_amdgcn_cvt_pk_fp8_f32(c, d, r, true);
  return (uint32_t)r;
}

// bijective row permutation for B staging: LDS row 16ni+fr holds global
// col 4fr+ni -> each lane's 4 ni-values are 4 consecutive columns.
__device__ __forceinline__ int sigma_row(int r) {
  return (r & 64) + ((r & 15) << 2) + ((r >> 4) & 3);
}

// bijective XCD-aware remap (m204 form; all grids here have nwg % 8 == 0):
// consecutive remapped ids share operand panels within one XCD's L2.
__device__ __forceinline__ void xcd_remap(int& bx, int& by, int& bz) {
  const int gx = gridDim.x, gy = gridDim.y;
  const int nwg = gx * gy * (int)gridDim.z;
  int lin = bx + gx * (by + gy * bz);
  int wg = (lin & 7) * (nwg >> 3) + (lin >> 3);
  bx = wg % gx;
  int t = wg / gx;
  by = t % gy;
  bz = t / gy;
}

enum { EPI_QK = 0, EPI_V = 1, EPI_OUT = 4, EPI_EXP = 2, EPI_PV = 5 };

// TN GEMM (bf16): C[M,N] = A[M,K] * B[N,K]^T, TMx128 tile, BK=64, NT thr,
// 16x16x32 MFMA, sigma-staged B + packed epilogue stores.
template <int EPI, int TM, int NT, bool SWZ>
__global__ __launch_bounds__(NT) void gemm_tn(
    const bf16_t* __restrict__ A, const bf16_t* __restrict__ B, int K,
    int lda, int ldb, long sAb, long sBb, long sCb, void* __restrict__ Cv,
    int ldc, const float* __restrict__ bias, const float* __restrict__ xres) {
  constexpr int NW = NT / 64;
  constexpr int WROWS = TM / (NW / 2);
  constexpr int MI = WROWS / 16;
  constexpr int RB = NT / 8;   // rows staged per batch
  constexpr int AB = TM / RB;  // A stage batches
  constexpr int BB = 128 / RB; // B stage batches
  constexpr int PMAX = AB > BB ? AB : BB;
  __shared__ bf16_t Asm[TM * 64];
  __shared__ bf16_t Bsm[128 * 64];

  const int tid = threadIdx.x;
  const int w = tid >> 6, l = tid & 63;
  int bx = blockIdx.x, by = blockIdx.y, bz = blockIdx.z;
  if constexpr (SWZ) xcd_remap(bx, by, bz);
  const int m0 = by * TM, n0 = bx * 128;

  const bf16_t* Ab = A + (long)bz * sAb + (long)m0 * lda;
  const bf16_t* Bb = B + (long)bz * sBb + (long)n0 * ldb;

  const int r0 = 8 * w + (l >> 3);
  const int schunk = (l & 7) ^ (l >> 3);
  const bf16_t* ga = Ab + (long)r0 * lda + schunk * 8;
  bf16_t* lA = Asm + (8 * w) * 64;
  bf16_t* lB = Bsm + (8 * w) * 64;

  const int wr = w >> 1, wc = w & 1;
  const int fr = l & 15, fq = l >> 4, l7 = l & 7;

  floatx4 acc[MI][4];
  floatx4 zz = {0.f, 0.f, 0.f, 0.f};
#pragma unroll
  for (int i = 0; i < MI; i++)
#pragma unroll
    for (int j = 0; j < 4; j++) acc[i][j] = zz;

  for (int kb = 0; kb < K; kb += 64) {
#pragma unroll
    for (int p = 0; p < PMAX; p++) {
      if (p < AB) ld_g2l(ga + (long)(p * RB) * lda + kb, lA + p * RB * 64);
      if (p < BB) {
        const int sig = sigma_row(r0 + RB * p);  // B rows sigma-permuted
        ld_g2l(Bb + (long)sig * ldb + schunk * 8 + kb, lB + p * RB * 64);
      }
    }
    __syncthreads();
#pragma unroll
    for (int ks = 0; ks < 2; ks++) {
      bf16x8 af[MI], bfv[4];
      const int ch = (ks * 4 + fq);
#pragma unroll
      for (int mi = 0; mi < MI; mi++) {
        int row = wr * WROWS + mi * 16 + fr;
        af[mi] = *(const bf16x8*)(Asm + row * 64 + ((ch ^ l7) * 8));
      }
#pragma unroll
      for (int ni = 0; ni < 4; ni++) {
        int row = wc * 64 + ni * 16 + fr;  // row&7 == l7
        bfv[ni] = *(const bf16x8*)(Bsm + row * 64 + ((ch ^ l7) * 8));
      }
#pragma unroll
      for (int mi = 0; mi < MI; mi++)
#pragma unroll
        for (int ni = 0; ni < 4; ni++)
          acc[mi][ni] = __builtin_amdgcn_mfma_f32_16x16x32_bf16(
              af[mi], bfv[ni], acc[mi][ni], 0, 0, 0);
    }
    __syncthreads();
  }

  // epilogue: sigma staging => MFMA ni, lane fr holds global col 4fr+ni
  const int rb = fq * 4;
  const int gcolb = n0 + wc * 64 + 4 * fr;
#pragma unroll
  for (int mi = 0; mi < MI; mi++) {
#pragma unroll
    for (int i = 0; i < 4; i++) {
      const int grow = m0 + wr * WROWS + mi * 16 + rb + i;
      float v0 = acc[mi][0][i], v1 = acc[mi][1][i];
      float v2 = acc[mi][2][i], v3 = acc[mi][3][i];
      if constexpr (EPI == EPI_QK) {
        // fp8 q||k output (q side pre-scaled via weights)
        const float4 b4 = *(const float4*)(bias + gcolb);
        *(uint32_t*)((uint8_t*)Cv + (long)bz * sCb + (long)grow * ldc +
                     gcolb) =
            pk_fp8x4(v0 + b4.x, v1 + b4.y, v2 + b4.z, v3 + b4.w);
      } else if constexpr (EPI == EPI_V) {
        const float bb = bias[grow];
        uint32_t d = pk_fp8x4(v0 + bb, v1 + bb, v2 + bb, v3 + bb);
        *(uint32_t*)((uint8_t*)Cv + (long)bz * sCb + (long)grow * ldc +
                     gcolb) = d;
      } else {  // EPI_OUT: grow = out channel, gcolb = b*P+p (4-aligned)
        int ob = gcolb >> 12, op = gcolb & 4095;
        long o = ((long)ob * CDIM + grow) * PDIM + op;
        const float4 xr = *(const float4*)(xres + o);
        const float bb = bias[grow];
        float4 ov = {v0 + bb + xr.x, v1 + bb + xr.y, v2 + bb + xr.z,
                     v3 + bb + xr.w};
        *(float4*)((float*)Cv + o) = ov;
      }
    }
  }
}

// fp8 TN GEMM via MX-scaled MFMA: C[M,N] op( A[M,K] * B[N,K]^T * 2^(SA-127) )
// TMx128 tile, BK=128, NT thr, mfma_scale_f32_16x16x128_f8f6f4.
// EPI_EXP: C = fp8(exp2(acc)); row-sum partials -> rsum[(bz*64+bx*2+wc)*P+r]
//          (non-atomic; rsum arg = part2 buffer).
// EPI_PV : C = bf16(acc / rsum[row]).
template <int EPI, int TM, int SA, int NT>
__global__ __launch_bounds__(NT) void gemm_f8(
    const uint8_t* __restrict__ A, const uint8_t* __restrict__ B, int K,
    int lda, int ldb, long sAb, long sBb, long sCb, void* __restrict__ Cv,
    int ldc, float* __restrict__ rsum) {
  constexpr int NW = NT / 64;
  constexpr int WROWS = TM / (NW / 2);
  constexpr int MI = WROWS / 16;
  constexpr int RB = NT / 8;
  constexpr int AB = TM / RB;
  constexpr int BB = 128 / RB;
  constexpr int PMAX = AB > BB ? AB : BB;
  __shared__ uint8_t Asm[TM * 128];
  __shared__ uint8_t Bsm[128 * 128];

  const int tid = threadIdx.x;
  const int w = tid >> 6, l = tid & 63;
  int bx = blockIdx.x, by = blockIdx.y, bz = blockIdx.z;
  xcd_remap(bx, by, bz);
  const int m0 = by * TM, n0 = bx * 128;

  const uint8_t* Ab = A + (long)bz * sAb + (long)m0 * lda;
  const uint8_t* Bb = B + (long)bz * sBb + (long)n0 * ldb;

  const int r0 = 8 * w + (l >> 3);
  const int schunk = (l & 7) ^ (l >> 3);
  const uint8_t* ga = Ab + (long)r0 * lda + schunk * 16;
  uint8_t* lA = Asm + (8 * w) * 128;
  uint8_t* lB = Bsm + (8 * w) * 128;

  const int wr = w >> 1, wc = w & 1;
  const int fr = l & 15, fq = l >> 4, l7 = l & 7;

  floatx4 acc[MI][4];
#pragma unroll
  for (int i = 0; i < MI; i++)
#pragma unroll
    for (int j = 0; j < 4; j++) acc[i][j] = floatx4{0.f, 0.f, 0.f, 0.f};

  const int s0 = ((2 * fq) ^ l7) * 16;
  const int s1 = ((2 * fq + 1) ^ l7) * 16;

  for (int kb = 0; kb < K; kb += 128) {
#pragma unroll
    for (int p = 0; p < PMAX; p++) {
      if (p < AB) ld_g2l(ga + (long)(p * RB) * lda + kb, lA + p * RB * 128);
      if (p < BB) {
        const int sig = sigma_row(r0 + RB * p);  // B rows sigma-permuted
        ld_g2l(Bb + (long)sig * ldb + schunk * 16 + kb, lB + p * RB * 128);
      }
    }
    __syncthreads();

    intx8 af[MI];
#pragma unroll
    for (int mi = 0; mi < MI; mi++) {
      const uint8_t* base = Asm + (wr * WROWS + mi * 16 + fr) * 128;
      uint4 x0 = *(const uint4*)(base + s0);
      uint4 x1 = *(const uint4*)(base + s1);
      af[mi] = intx8{(int)x0.x, (int)x0.y, (int)x0.z, (int)x0.w,
                     (int)x1.x, (int)x1.y, (int)x1.z, (int)x1.w};
    }
#pragma unroll
    for (int ni = 0; ni < 4; ni++) {
      const uint8_t* base = Bsm + (wc * 64 + ni * 16 + fr) * 128;  // row&7==l7
      uint4 y0 = *(const uint4*)(base + s0);
      uint4 y1 = *(const uint4*)(base + s1);
      intx8 bf = intx8{(int)y0.x, (int)y0.y, (int)y0.z, (int)y0.w,
                       (int)y1.x, (int)y1.y, (int)y1.z, (int)y1.w};
#pragma unroll
      for (int mi = 0; mi < MI; mi++)
        acc[mi][ni] = __builtin_amdgcn_mfma_scale_f32_16x16x128_f8f6f4(
            af[mi], bf, acc[mi][ni], 0, 0, 0, SA, 0, 127);
    }
    __syncthreads();
  }

  const int rb = fq * 4;
  const int gcolb = n0 + wc * 64 + 4 * fr;
#pragma unroll
  for (int mi = 0; mi < MI; mi++) {
#pragma unroll
    for (int i = 0; i < 4; i++) {
      const int grow = m0 + wr * WROWS + mi * 16 + rb + i;
      if constexpr (EPI == EPI_EXP) {
        // acc already in log2 units (weight prescale + 2^-4 MX scale)
        float p0 = exp2f(acc[mi][0][i]), p1 = exp2f(acc[mi][1][i]);
        float p2 = exp2f(acc[mi][2][i]), p3 = exp2f(acc[mi][3][i]);
        *(uint32_t*)((uint8_t*)Cv + (long)bz * sCb + (long)grow * ldc +
                     gcolb) = pk_fp8x4(p0, p1, p2, p3);
        float rowacc = (p0 + p1) + (p2 + p3);
        rowacc += __shfl_xor(rowacc, 1);
        rowacc += __shfl_xor(rowacc, 2);
        rowacc += __shfl_xor(rowacc, 4);
        rowacc += __shfl_xor(rowacc, 8);
        if (fr == 0)
          rsum[((long)(bz * 64 + bx * 2 + wc)) * PDIM + grow] = rowacc;
      } else {  // EPI_PV
        const float inv =
            __builtin_amdgcn_rcpf(rsum[(long)bz * PDIM + grow]);
        bf16x4 o = {(bf16_t)(acc[mi][0][i] * inv),
                    (bf16_t)(acc[mi][1][i] * inv),
                    (bf16_t)(acc[mi][2][i] * inv),
                    (bf16_t)(acc[mi][3][i] * inv)};
        *(bf16x4*)((bf16_t*)Cv + (long)bz * sCb + (long)grow * ldc + gcolb) =
            o;
      }
    }
  }
}

// rsum[bz*P + r] = sum over 64 slices of part2[bz][slice][r]
__global__ __launch_bounds__(256) void rsum_reduce(
    const float* __restrict__ part2, float* __restrict__ rsum) {
  const int r = blockIdx.x * 256 + threadIdx.x;  // 0..16383
  const int bz = r >> 12, row = r & 4095;
  const float* p = part2 + ((long)bz * 64) * PDIM + row;
  float s = 0.f;
#pragma unroll
  for (int j = 0; j < 64; j++) s += p[(long)j * PDIM];
  rsum[r] = s;
}

// Stage 1: partial sums. Block i reads x[i*8192 .. +8192), writes (sum, sumsq).
__global__ __launch_bounds__(256) void gn_stats(const float* __restrict__ x,
                                                float2* __restrict__ part) {
  const int i = blockIdx.x;
  const float4* xp = (const float4*)(x + (long)i * 8192);
  float s0 = 0.f, s1 = 0.f;
  for (int j = threadIdx.x; j < 2048; j += 256) {
    float4 v = xp[j];
    s0 += v.x + v.y + v.z + v.w;
    s1 += v.x * v.x + v.y * v.y + v.z * v.z + v.w * v.w;
  }
  for (int o = 32; o; o >>= 1) {
    s0 += __shfl_xor(s0, o);
    s1 += __shfl_xor(s1, o);
  }
  __shared__ float r0[4], r1[4];
  if ((threadIdx.x & 63) == 0) {
    r0[threadIdx.x >> 6] = s0;
    r1[threadIdx.x >> 6] = s1;
  }
  __syncthreads();
  if (threadIdx.x == 0)
    part[i] = make_float2(r0[0] + r0[1] + r0[2] + r0[3],
                          r1[0] + r1[1] + r1[2] + r1[3]);
}

// Stage 2: normalize + transpose via LDS tile. Block = (b, 32 p-rows).
__global__ __launch_bounds__(256) void gn_norm(
    const float* __restrict__ x, const float* __restrict__ gamma,
    const float* __restrict__ beta, const float2* __restrict__ part,
    bf16_t* __restrict__ h_t) {
  const int b = blockIdx.x >> 7;
  const int p0 = (blockIdx.x & 127) * 32;
  const int t = threadIdx.x;
  __shared__ float gmS[512], btS[512];
  __shared__ float gmean[32], grstd[32];
  __shared__ __align__(16) bf16_t tile[32 * 520];

  if (t < 32) {
    const float2* pp = part + (b * 32 + t) * 8;
    float s0 = 0.f, s1 = 0.f;
#pragma unroll
    for (int s = 0; s < 8; s++) {
      float2 v = pp[s];
      s0 += v.x;
      s1 += v.y;
    }
    float mean = s0 * (1.f / 65536.f);
    float var = s1 * (1.f / 65536.f) - mean * mean;
    gmean[t] = mean;
    grstd[t] = rsqrtf(var + 1e-6f);
  }
  __syncthreads();
  for (int c = t; c < 512; c += 256) {
    float g = gamma[c] * grstd[c >> 4];
    gmS[c] = g;
    btS[c] = beta[c] - gmean[c >> 4] * g;
  }
  __syncthreads();

  const int cc = t >> 3, pcol = (t & 7) * 4;
  for (int pass = 0; pass < 16; pass++) {
    int c = pass * 32 + cc;
    float4 v = *(const float4*)(x + ((long)(b * 512 + c)) * 4096 + p0 + pcol);
    float g = gmS[c], bb = btS[c];
    tile[(pcol + 0) * 520 + c] = (bf16_t)(v.x * g + bb);
    tile[(pcol + 1) * 520 + c] = (bf16_t)(v.y * g + bb);
    tile[(pcol + 2) * 520 + c] = (bf16_t)(v.z * g + bb);
    tile[(pcol + 3) * 520 + c] = (bf16_t)(v.w * g + bb);
  }
  __syncthreads();
  const int p = t >> 3;
  bf16_t* orow = h_t + ((long)(b * 4096 + p0 + p)) * 512;
  const bf16_t* trow = tile + p * 520;
#pragma unroll
  for (int j = 0; j < 8; j++) {
    int ch = (t & 7) + 8 * j;
    *(uint4*)(orow + ch * 8) = *(const uint4*)(trow + ch * 8);
  }
}

// wq,bq prescaled by (log2e/sqrt(512)) / 2^-4 so the EXP GEMM's e8m0
// A-scale of 123 (2^-4) yields log2-domain scores directly.
__global__ __launch_bounds__(256) void cvt_weights(
    const float* __restrict__ wq, const float* __restrict__ wk,
    const float* __restrict__ wv, const float* __restrict__ wo,
    const float* __restrict__ bq, const float* __restrict__ bk,
    bf16_t* __restrict__ out, float* __restrict__ bqk) {
  constexpr float QW = 1.02013936f;  // (1/sqrt(512))*log2(e) / 2^-4
  int i = blockIdx.x * 256 + threadIdx.x;
  out[i] = (bf16_t)(wq[i] * QW);
  out[262144 + i] = (bf16_t)wk[i];
  out[2 * 262144 + i] = (bf16_t)wv[i];
  out[3 * 262144 + i] = (bf16_t)wo[i];
  if (i < 512)
    bqk[i] = bq[i] * QW;
  else if (i < 1024)
    bqk[i] = bk[i - 512];
}

extern "C" void kernel_launch(void* const* d_in, const int* in_sizes, int n_in,
                              void* d_out, int out_size, void* d_ws,
                              size_t ws_size, hipStream_t stream) {
  const float* x = (const float*)d_in[0];
  const float* gamma = (const float*)d_in[1];
  const float* beta = (const float*)d_in[2];
  const float* wq = (const float*)d_in[3];
  const float* bq = (const float*)d_in[4];
  const float* wk = (const float*)d_in[5];
  const float* bk = (const float*)d_in[6];
  const float* wv = (const float*)d_in[7];
  const float* bv = (const float*)d_in[8];
  const float* wo = (const float*)d_in[9];
  const float* bo = (const float*)d_in[10];

  char* ws = (char*)d_ws;
  bf16_t* h_t = (bf16_t*)(ws);                  // [16384,512] bf16  @0
  float* part2 = (float*)(ws);                  // [4,64,4096] f32 (aliases
                                                //  h_t — dead after V proj)
  uint8_t* qk8 = (uint8_t*)(ws + (16l << 20));  // [16384,1024] fp8  @16MB
  uint8_t* v_c = (uint8_t*)(ws + (48l << 20));  // [512,16384] fp8   @48MB
  bf16_t* h_at = (bf16_t*)(ws + (64l << 20));   // [16384,512] bf16  @64MB
  bf16_t* w_b = (bf16_t*)(ws + (80l << 20));    // 4x[512,512] bf16  @80MB
  float2* part = (float2*)(ws + (83l << 20));   // [1024] partials   @83MB
  float* bqk = (float*)(ws + (83l << 20) + (64l << 10));    // [1024]
  float* rsum = (float*)(ws + (83l << 20) + (128l << 10));  // [4*4096]
  uint8_t* Sbuf = (uint8_t*)(ws + (84l << 20)); // [4,4096,4096] fp8 @84MB

  const long sQK8 = (long)PDIM * 1024;  // bytes per batch of qk8
  const long sS = (long)PDIM * PDIM;    // 16777216

  cvt_weights<<<1024, 256, 0, stream>>>(wq, wk, wv, wo, bq, bk, w_b, bqk);
  gn_stats<<<1024, 256, 0, stream>>>(x, part);
  gn_norm<<<512, 256, 0, stream>>>(x, gamma, beta, part, h_t);
  // fused q|k projection -> fp8: B = [wq;wk] rows 0..1023, bias bqk
  gemm_tn<EPI_QK, 256, 512, true><<<dim3(8, 64, 1), 512, 0, stream>>>(
      h_t, w_b, 512, 512, 512, 0, 0, 0, qk8, 1024, bqk, nullptr);
  gemm_tn<EPI_V, 64, 256, false><<<dim3(128, 8, 1), 256, 0, stream>>>(
      w_b + 2 * 262144, h_t, 512, 512, 512, 0, 0, 0, v_c, 16384, bv, nullptr);
  // P = exp2(2^-4 * q8 k8^T) fp8 (unnormalized) + row-sum partials
  gemm_f8<EPI_EXP, 256, 123, 512><<<dim3(32, 16, 4), 512, 0, stream>>>(
      qk8, qk8 + 512, 512, 1024, 1024, sQK8, sQK8, sS, Sbuf, 4096, part2);
  rsum_reduce<<<64, 256, 0, stream>>>(part2, rsum);
  // h_at = (P @ v^T) / rsum  — MX-fp8 K=128 MFMA
  gemm_f8<EPI_PV, 128, 127, 256><<<dim3(4, 32, 4), 256, 0, stream>>>(
      Sbuf, v_c, 4096, 4096, 16384, sS, 4096, (long)PDIM * CDIM, h_at, 512,
      rsum);
  gemm_tn<EPI_OUT, 64, 256, false><<<dim3(128, 8, 1), 256, 0, stream>>>(
      w_b + 3 * 262144, h_at, 512, 512, 512, 0, 0, 0, d_out, 4096, bo, x);
}

// Round 3
// 263.279 us; speedup vs baseline: 1.1576x; 1.1576x over previous
//
#include <hip/hip_runtime.h>
#include <stdint.h>

// SpatialSelfAttention: B=4, C=512, P=4096, 32 groups.
// Pipeline (round 10: small-tile EXP + swizzle, rsum via ones-MFMA in PV):
//   1. cvt weights fp32->bf16 (wq,bq prescaled by 1.02014 = qscale2/2^-4)
//   2. gn_stats + gn_norm -> h_t [B*P, C] bf16 (LDS tile transpose)
//   3. qk8 = h_t @ [wq;wk]^T  [B*P, 1024] fp8 e4m3
//      v_c = wv @ h_t^T       [C, B*P]  fp8 e4m3
//   4. P[b] = exp2(2^-4 * q8[b] @ k8[b]^T)  [P,P] fp8 via MX-scaled
//      mfma_scale_f32_16x16x128_f8f6f4 (A-scale e8m0=123 -> 2^-4).
//      128x128 tile, 256 thr, 4096 blocks (round-1 shape: latency-hiding
//      via block TLP beats bigger tiles in this 4-K-iter regime).
//      NO row sums here (removed shfl-reduce epilogue).
//   5. h_at[b] = (P[b] @ v_c[b]^T) / rsum  [P, C] bf16, 128x128 MX-fp8.
//      rsum computed IN-KERNEL via extra ones-B MFMA (P @ 1, fp8 1.0=0x38;
//      all-equal B-frag is lane-layout-proof). Self-consistent: divides by
//      the sum of actual fp8-rounded P.
//   6. out = wo @ h_at^T + bo + x  [C, B*P] fp32 == d_out layout
// QK/EXP/PV use bijective XCD swizzle; V/OUT keep default (already local).

typedef __bf16 bf16_t;
typedef __attribute__((ext_vector_type(4))) __bf16 bf16x4;
typedef __attribute__((ext_vector_type(8))) __bf16 bf16x8;
typedef __attribute__((ext_vector_type(4))) float floatx4;
typedef __attribute__((ext_vector_type(8))) int intx8;

constexpr int CDIM = 512;
constexpr int PDIM = 4096;

__device__ __forceinline__ void ld_g2l(const void* g, void* l) {
  __builtin_amdgcn_global_load_lds(
      (const __attribute__((address_space(1))) void*)g,
      (__attribute__((address_space(3))) void*)l,
      16, 0, 0);
}

__device__ __forceinline__ uint32_t pk_fp8x4(float a, float b, float c,
                                             float d) {
  int r = __builtin_amdgcn_cvt_pk_fp8_f32(a, b, 0, false);
  r = __builtin_amdgcn_cvt_pk_fp8_f32(c, d, r, true);
  return (uint32_t)r;
}

// bijective row permutation for B staging: LDS row 16ni+fr holds global
// col 4fr+ni -> each lane's 4 ni-values are 4 consecutive columns.
__device__ __forceinline__ int sigma_row(int r) {
  return (r & 64) + ((r & 15) << 2) + ((r >> 4) & 3);
}

// bijective XCD-aware remap (m204 form; all grids here have nwg % 8 == 0):
// consecutive remapped ids share operand panels within one XCD's L2.
__device__ __forceinline__ void xcd_remap(int& bx, int& by, int& bz) {
  const int gx = gridDim.x, gy = gridDim.y;
  const int nwg = gx * gy * (int)gridDim.z;
  int lin = bx + gx * (by + gy * bz);
  int wg = (lin & 7) * (nwg >> 3) + (lin >> 3);
  bx = wg % gx;
  int t = wg / gx;
  by = t % gy;
  bz = t / gy;
}

enum { EPI_QK = 0, EPI_V = 1, EPI_OUT = 4, EPI_EXP = 2, EPI_PV = 5 };

// TN GEMM (bf16): C[M,N] = A[M,K] * B[N,K]^T, TMx128 tile, BK=64, NT thr,
// 16x16x32 MFMA, sigma-staged B + packed epilogue stores.
template <int EPI, int TM, int NT, bool SWZ>
__global__ __launch_bounds__(NT) void gemm_tn(
    const bf16_t* __restrict__ A, const bf16_t* __restrict__ B, int K,
    int lda, int ldb, long sAb, long sBb, long sCb, void* __restrict__ Cv,
    int ldc, const float* __restrict__ bias, const float* __restrict__ xres) {
  constexpr int NW = NT / 64;
  constexpr int WROWS = TM / (NW / 2);
  constexpr int MI = WROWS / 16;
  constexpr int RB = NT / 8;   // rows staged per batch
  constexpr int AB = TM / RB;  // A stage batches
  constexpr int BB = 128 / RB; // B stage batches
  constexpr int PMAX = AB > BB ? AB : BB;
  __shared__ bf16_t Asm[TM * 64];
  __shared__ bf16_t Bsm[128 * 64];

  const int tid = threadIdx.x;
  const int w = tid >> 6, l = tid & 63;
  int bx = blockIdx.x, by = blockIdx.y, bz = blockIdx.z;
  if constexpr (SWZ) xcd_remap(bx, by, bz);
  const int m0 = by * TM, n0 = bx * 128;

  const bf16_t* Ab = A + (long)bz * sAb + (long)m0 * lda;
  const bf16_t* Bb = B + (long)bz * sBb + (long)n0 * ldb;

  const int r0 = 8 * w + (l >> 3);
  const int schunk = (l & 7) ^ (l >> 3);
  const bf16_t* ga = Ab + (long)r0 * lda + schunk * 8;
  bf16_t* lA = Asm + (8 * w) * 64;
  bf16_t* lB = Bsm + (8 * w) * 64;

  const int wr = w >> 1, wc = w & 1;
  const int fr = l & 15, fq = l >> 4, l7 = l & 7;

  floatx4 acc[MI][4];
  floatx4 zz = {0.f, 0.f, 0.f, 0.f};
#pragma unroll
  for (int i = 0; i < MI; i++)
#pragma unroll
    for (int j = 0; j < 4; j++) acc[i][j] = zz;

  for (int kb = 0; kb < K; kb += 64) {
#pragma unroll
    for (int p = 0; p < PMAX; p++) {
      if (p < AB) ld_g2l(ga + (long)(p * RB) * lda + kb, lA + p * RB * 64);
      if (p < BB) {
        const int sig = sigma_row(r0 + RB * p);  // B rows sigma-permuted
        ld_g2l(Bb + (long)sig * ldb + schunk * 8 + kb, lB + p * RB * 64);
      }
    }
    __syncthreads();
#pragma unroll
    for (int ks = 0; ks < 2; ks++) {
      bf16x8 af[MI], bfv[4];
      const int ch = (ks * 4 + fq);
#pragma unroll
      for (int mi = 0; mi < MI; mi++) {
        int row = wr * WROWS + mi * 16 + fr;
        af[mi] = *(const bf16x8*)(Asm + row * 64 + ((ch ^ l7) * 8));
      }
#pragma unroll
      for (int ni = 0; ni < 4; ni++) {
        int row = wc * 64 + ni * 16 + fr;  // row&7 == l7
        bfv[ni] = *(const bf16x8*)(Bsm + row * 64 + ((ch ^ l7) * 8));
      }
#pragma unroll
      for (int mi = 0; mi < MI; mi++)
#pragma unroll
        for (int ni = 0; ni < 4; ni++)
          acc[mi][ni] = __builtin_amdgcn_mfma_f32_16x16x32_bf16(
              af[mi], bfv[ni], acc[mi][ni], 0, 0, 0);
    }
    __syncthreads();
  }

  // epilogue: sigma staging => MFMA ni, lane fr holds global col 4fr+ni
  const int rb = fq * 4;
  const int gcolb = n0 + wc * 64 + 4 * fr;
#pragma unroll
  for (int mi = 0; mi < MI; mi++) {
#pragma unroll
    for (int i = 0; i < 4; i++) {
      const int grow = m0 + wr * WROWS + mi * 16 + rb + i;
      float v0 = acc[mi][0][i], v1 = acc[mi][1][i];
      float v2 = acc[mi][2][i], v3 = acc[mi][3][i];
      if constexpr (EPI == EPI_QK) {
        // fp8 q||k output (q side pre-scaled via weights)
        const float4 b4 = *(const float4*)(bias + gcolb);
        *(uint32_t*)((uint8_t*)Cv + (long)bz * sCb + (long)grow * ldc +
                     gcolb) =
            pk_fp8x4(v0 + b4.x, v1 + b4.y, v2 + b4.z, v3 + b4.w);
      } else if constexpr (EPI == EPI_V) {
        const float bb = bias[grow];
        uint32_t d = pk_fp8x4(v0 + bb, v1 + bb, v2 + bb, v3 + bb);
        *(uint32_t*)((uint8_t*)Cv + (long)bz * sCb + (long)grow * ldc +
                     gcolb) = d;
      } else {  // EPI_OUT: grow = out channel, gcolb = b*P+p (4-aligned)
        int ob = gcolb >> 12, op = gcolb & 4095;
        long o = ((long)ob * CDIM + grow) * PDIM + op;
        const float4 xr = *(const float4*)(xres + o);
        const float bb = bias[grow];
        float4 ov = {v0 + bb + xr.x, v1 + bb + xr.y, v2 + bb + xr.z,
                     v3 + bb + xr.w};
        *(float4*)((float*)Cv + o) = ov;
      }
    }
  }
}

// fp8 TN GEMM via MX-scaled MFMA: C[M,N] op( A[M,K] * B[N,K]^T * 2^(SA-127) )
// TMx128 tile, BK=128, NT thr, mfma_scale_f32_16x16x128_f8f6f4.
// EPI_EXP: C = fp8(exp2(acc)). No row sums (moved to PV's ones-MFMA).
// EPI_PV : C = bf16(acc / rowsum) with rowsum = P @ 1 via extra MFMA
//          (B-frag = splat fp8 1.0 = 0x38; all-equal frag is layout-proof).
template <int EPI, int TM, int SA, int NT>
__global__ __launch_bounds__(NT) void gemm_f8(
    const uint8_t* __restrict__ A, const uint8_t* __restrict__ B, int K,
    int lda, int ldb, long sAb, long sBb, long sCb, void* __restrict__ Cv,
    int ldc) {
  constexpr int NW = NT / 64;
  constexpr int WROWS = TM / (NW / 2);
  constexpr int MI = WROWS / 16;
  constexpr int RB = NT / 8;
  constexpr int AB = TM / RB;
  constexpr int BB = 128 / RB;
  constexpr int PMAX = AB > BB ? AB : BB;
  __shared__ uint8_t Asm[TM * 128];
  __shared__ uint8_t Bsm[128 * 128];

  const int tid = threadIdx.x;
  const int w = tid >> 6, l = tid & 63;
  int bx = blockIdx.x, by = blockIdx.y, bz = blockIdx.z;
  xcd_remap(bx, by, bz);
  const int m0 = by * TM, n0 = bx * 128;

  const uint8_t* Ab = A + (long)bz * sAb + (long)m0 * lda;
  const uint8_t* Bb = B + (long)bz * sBb + (long)n0 * ldb;

  const int r0 = 8 * w + (l >> 3);
  const int schunk = (l & 7) ^ (l >> 3);
  const uint8_t* ga = Ab + (long)r0 * lda + schunk * 16;
  uint8_t* lA = Asm + (8 * w) * 128;
  uint8_t* lB = Bsm + (8 * w) * 128;

  const int wr = w >> 1, wc = w & 1;
  const int fr = l & 15, fq = l >> 4, l7 = l & 7;

  floatx4 acc[MI][4];
  floatx4 accr[MI];  // PV row sums (P @ ones)
#pragma unroll
  for (int i = 0; i < MI; i++) {
#pragma unroll
    for (int j = 0; j < 4; j++) acc[i][j] = floatx4{0.f, 0.f, 0.f, 0.f};
    accr[i] = floatx4{0.f, 0.f, 0.f, 0.f};
  }

  const int s0 = ((2 * fq) ^ l7) * 16;
  const int s1 = ((2 * fq + 1) ^ l7) * 16;

  for (int kb = 0; kb < K; kb += 128) {
#pragma unroll
    for (int p = 0; p < PMAX; p++) {
      if (p < AB) ld_g2l(ga + (long)(p * RB) * lda + kb, lA + p * RB * 128);
      if (p < BB) {
        const int sig = sigma_row(r0 + RB * p);  // B rows sigma-permuted
        ld_g2l(Bb + (long)sig * ldb + schunk * 16 + kb, lB + p * RB * 128);
      }
    }
    __syncthreads();

    intx8 af[MI];
#pragma unroll
    for (int mi = 0; mi < MI; mi++) {
      const uint8_t* base = Asm + (wr * WROWS + mi * 16 + fr) * 128;
      uint4 x0 = *(const uint4*)(base + s0);
      uint4 x1 = *(const uint4*)(base + s1);
      af[mi] = intx8{(int)x0.x, (int)x0.y, (int)x0.z, (int)x0.w,
                     (int)x1.x, (int)x1.y, (int)x1.z, (int)x1.w};
    }
#pragma unroll
    for (int ni = 0; ni < 4; ni++) {
      const uint8_t* base = Bsm + (wc * 64 + ni * 16 + fr) * 128;  // row&7==l7
      uint4 y0 = *(const uint4*)(base + s0);
      uint4 y1 = *(const uint4*)(base + s1);
      intx8 bf = intx8{(int)y0.x, (int)y0.y, (int)y0.z, (int)y0.w,
                       (int)y1.x, (int)y1.y, (int)y1.z, (int)y1.w};
#pragma unroll
      for (int mi = 0; mi < MI; mi++)
        acc[mi][ni] = __builtin_amdgcn_mfma_scale_f32_16x16x128_f8f6f4(
            af[mi], bf, acc[mi][ni], 0, 0, 0, SA, 0, 127);
    }
    if constexpr (EPI == EPI_PV) {
      const int one8 = 0x38383838;  // 4x fp8 e4m3 1.0
      const intx8 ones = {one8, one8, one8, one8, one8, one8, one8, one8};
#pragma unroll
      for (int mi = 0; mi < MI; mi++)
        accr[mi] = __builtin_amdgcn_mfma_scale_f32_16x16x128_f8f6f4(
            af[mi], ones, accr[mi], 0, 0, 0, SA, 0, 127);
    }
    __syncthreads();
  }

  const int rb = fq * 4;
  const int gcolb = n0 + wc * 64 + 4 * fr;
#pragma unroll
  for (int mi = 0; mi < MI; mi++) {
#pragma unroll
    for (int i = 0; i < 4; i++) {
      const int grow = m0 + wr * WROWS + mi * 16 + rb + i;
      if constexpr (EPI == EPI_EXP) {
        // acc already in log2 units (weight prescale + 2^-4 MX scale)
        float p0 = exp2f(acc[mi][0][i]), p1 = exp2f(acc[mi][1][i]);
        float p2 = exp2f(acc[mi][2][i]), p3 = exp2f(acc[mi][3][i]);
        *(uint32_t*)((uint8_t*)Cv + (long)bz * sCb + (long)grow * ldc +
                     gcolb) = pk_fp8x4(p0, p1, p2, p3);
      } else {  // EPI_PV: every column of accr == rowsum for this row
        const float inv = __builtin_amdgcn_rcpf(accr[mi][i]);
        bf16x4 o = {(bf16_t)(acc[mi][0][i] * inv),
                    (bf16_t)(acc[mi][1][i] * inv),
                    (bf16_t)(acc[mi][2][i] * inv),
                    (bf16_t)(acc[mi][3][i] * inv)};
        *(bf16x4*)((bf16_t*)Cv + (long)bz * sCb + (long)grow * ldc + gcolb) =
            o;
      }
    }
  }
}

// Stage 1: partial sums. Block i reads x[i*8192 .. +8192), writes (sum, sumsq).
__global__ __launch_bounds__(256) void gn_stats(const float* __restrict__ x,
                                                float2* __restrict__ part) {
  const int i = blockIdx.x;
  const float4* xp = (const float4*)(x + (long)i * 8192);
  float s0 = 0.f, s1 = 0.f;
  for (int j = threadIdx.x; j < 2048; j += 256) {
    float4 v = xp[j];
    s0 += v.x + v.y + v.z + v.w;
    s1 += v.x * v.x + v.y * v.y + v.z * v.z + v.w * v.w;
  }
  for (int o = 32; o; o >>= 1) {
    s0 += __shfl_xor(s0, o);
    s1 += __shfl_xor(s1, o);
  }
  __shared__ float r0[4], r1[4];
  if ((threadIdx.x & 63) == 0) {
    r0[threadIdx.x >> 6] = s0;
    r1[threadIdx.x >> 6] = s1;
  }
  __syncthreads();
  if (threadIdx.x == 0)
    part[i] = make_float2(r0[0] + r0[1] + r0[2] + r0[3],
                          r1[0] + r1[1] + r1[2] + r1[3]);
}

// Stage 2: normalize + transpose via LDS tile. Block = (b, 32 p-rows).
__global__ __launch_bounds__(256) void gn_norm(
    const float* __restrict__ x, const float* __restrict__ gamma,
    const float* __restrict__ beta, const float2* __restrict__ part,
    bf16_t* __restrict__ h_t) {
  const int b = blockIdx.x >> 7;
  const int p0 = (blockIdx.x & 127) * 32;
  const int t = threadIdx.x;
  __shared__ float gmS[512], btS[512];
  __shared__ float gmean[32], grstd[32];
  __shared__ __align__(16) bf16_t tile[32 * 520];

  if (t < 32) {
    const float2* pp = part + (b * 32 + t) * 8;
    float s0 = 0.f, s1 = 0.f;
#pragma unroll
    for (int s = 0; s < 8; s++) {
      float2 v = pp[s];
      s0 += v.x;
      s1 += v.y;
    }
    float mean = s0 * (1.f / 65536.f);
    float var = s1 * (1.f / 65536.f) - mean * mean;
    gmean[t] = mean;
    grstd[t] = rsqrtf(var + 1e-6f);
  }
  __syncthreads();
  for (int c = t; c < 512; c += 256) {
    float g = gamma[c] * grstd[c >> 4];
    gmS[c] = g;
    btS[c] = beta[c] - gmean[c >> 4] * g;
  }
  __syncthreads();

  const int cc = t >> 3, pcol = (t & 7) * 4;
  for (int pass = 0; pass < 16; pass++) {
    int c = pass * 32 + cc;
    float4 v = *(const float4*)(x + ((long)(b * 512 + c)) * 4096 + p0 + pcol);
    float g = gmS[c], bb = btS[c];
    tile[(pcol + 0) * 520 + c] = (bf16_t)(v.x * g + bb);
    tile[(pcol + 1) * 520 + c] = (bf16_t)(v.y * g + bb);
    tile[(pcol + 2) * 520 + c] = (bf16_t)(v.z * g + bb);
    tile[(pcol + 3) * 520 + c] = (bf16_t)(v.w * g + bb);
  }
  __syncthreads();
  const int p = t >> 3;
  bf16_t* orow = h_t + ((long)(b * 4096 + p0 + p)) * 512;
  const bf16_t* trow = tile + p * 520;
#pragma unroll
  for (int j = 0; j < 8; j++) {
    int ch = (t & 7) + 8 * j;
    *(uint4*)(orow + ch * 8) = *(const uint4*)(trow + ch * 8);
  }
}

// wq,bq prescaled by (log2e/sqrt(512)) / 2^-4 so the EXP GEMM's e8m0
// A-scale of 123 (2^-4) yields log2-domain scores directly.
__global__ __launch_bounds__(256) void cvt_weights(
    const float* __restrict__ wq, const float* __restrict__ wk,
    const float* __restrict__ wv, const float* __restrict__ wo,
    const float* __restrict__ bq, const float* __restrict__ bk,
    bf16_t* __restrict__ out, float* __restrict__ bqk) {
  constexpr float QW = 1.02013936f;  // (1/sqrt(512))*log2(e) / 2^-4
  int i = blockIdx.x * 256 + threadIdx.x;
  out[i] = (bf16_t)(wq[i] * QW);
  out[262144 + i] = (bf16_t)wk[i];
  out[2 * 262144 + i] = (bf16_t)wv[i];
  out[3 * 262144 + i] = (bf16_t)wo[i];
  if (i < 512)
    bqk[i] = bq[i] * QW;
  else if (i < 1024)
    bqk[i] = bk[i - 512];
}

extern "C" void kernel_launch(void* const* d_in, const int* in_sizes, int n_in,
                              void* d_out, int out_size, void* d_ws,
                              size_t ws_size, hipStream_t stream) {
  const float* x = (const float*)d_in[0];
  const float* gamma = (const float*)d_in[1];
  const float* beta = (const float*)d_in[2];
  const float* wq = (const float*)d_in[3];
  const float* bq = (const float*)d_in[4];
  const float* wk = (const float*)d_in[5];
  const float* bk = (const float*)d_in[6];
  const float* wv = (const float*)d_in[7];
  const float* bv = (const float*)d_in[8];
  const float* wo = (const float*)d_in[9];
  const float* bo = (const float*)d_in[10];

  char* ws = (char*)d_ws;
  bf16_t* h_t = (bf16_t*)(ws);                  // [16384,512] bf16  @0
  uint8_t* qk8 = (uint8_t*)(ws + (16l << 20));  // [16384,1024] fp8  @16MB
  uint8_t* v_c = (uint8_t*)(ws + (48l << 20));  // [512,16384] fp8   @48MB
  bf16_t* h_at = (bf16_t*)(ws + (64l << 20));   // [16384,512] bf16  @64MB
  bf16_t* w_b = (bf16_t*)(ws + (80l << 20));    // 4x[512,512] bf16  @80MB
  float2* part = (float2*)(ws + (83l << 20));   // [1024] partials   @83MB
  float* bqk = (float*)(ws + (83l << 20) + (64l << 10));    // [1024]
  uint8_t* Sbuf = (uint8_t*)(ws + (84l << 20)); // [4,4096,4096] fp8 @84MB

  const long sQK8 = (long)PDIM * 1024;  // bytes per batch of qk8
  const long sS = (long)PDIM * PDIM;    // 16777216

  cvt_weights<<<1024, 256, 0, stream>>>(wq, wk, wv, wo, bq, bk, w_b, bqk);
  gn_stats<<<1024, 256, 0, stream>>>(x, part);
  gn_norm<<<512, 256, 0, stream>>>(x, gamma, beta, part, h_t);
  // fused q|k projection -> fp8: B = [wq;wk] rows 0..1023, bias bqk
  gemm_tn<EPI_QK, 128, 256, true><<<dim3(8, 128, 1), 256, 0, stream>>>(
      h_t, w_b, 512, 512, 512, 0, 0, 0, qk8, 1024, bqk, nullptr);
  gemm_tn<EPI_V, 64, 256, false><<<dim3(128, 8, 1), 256, 0, stream>>>(
      w_b + 2 * 262144, h_t, 512, 512, 512, 0, 0, 0, v_c, 16384, bv, nullptr);
  // P = exp2(2^-4 * q8 k8^T) fp8 (unnormalized; sums computed in PV)
  gemm_f8<EPI_EXP, 128, 123, 256><<<dim3(32, 32, 4), 256, 0, stream>>>(
      qk8, qk8 + 512, 512, 1024, 1024, sQK8, sQK8, sS, Sbuf, 4096);
  // h_at = (P @ v^T) / (P @ 1)  — MX-fp8 K=128 MFMA, rsum via ones-MFMA
  gemm_f8<EPI_PV, 128, 127, 256><<<dim3(4, 32, 4), 256, 0, stream>>>(
      Sbuf, v_c, 4096, 4096, 16384, sS, 4096, (long)PDIM * CDIM, h_at, 512);
  gemm_tn<EPI_OUT, 64, 256, false><<<dim3(128, 8, 1), 256, 0, stream>>>(
      w_b + 3 * 262144, h_at, 512, 512, 512, 0, 0, 0, d_out, 4096, bo, x);
}

// Round 4
// 257.991 us; speedup vs baseline: 1.1814x; 1.0205x over previous
//
#include <hip/hip_runtime.h>
#include <stdint.h>

// SpatialSelfAttention: B=4, C=512, P=4096, 32 groups.
// Pipeline (round 11: constant-propagation — kill VALU overhead):
//   Round-3 postmortem: EXP does only 64 MFMA/wave but ~4.4K VALU cyc/wave
//   (VALUBusy 54%). Sources: xcd_remap's 4 runtime int divides (~160cyc),
//   runtime K/lda/ldb/ldc forcing per-iter address muls, intx8 reg copies.
//   Fix: templatize K + all strides + grid dims (everything is compile-time
//   known, grids are pow2 -> shift/mask remap), full/partial K-unroll so
//   global offsets fold into load-immediate offsets. No layout/schedule/
//   numerics change vs round 3.
//   1. cvt weights fp32->bf16 (wq,bq prescaled by 1.02014 = qscale2/2^-4)
//   2. gn_stats + gn_norm -> h_t [B*P, C] bf16 (LDS tile transpose)
//   3. qk8 = h_t @ [wq;wk]^T  [B*P, 1024] fp8 e4m3
//      v_c = wv @ h_t^T       [C, B*P]  fp8 e4m3
//   4. P[b] = exp2(2^-4 * q8[b] @ k8[b]^T)  [P,P] fp8 via MX-scaled
//      mfma_scale_f32_16x16x128_f8f6f4 (A-scale e8m0=123 -> 2^-4).
//   5. h_at[b] = (P[b] @ v_c[b]^T) / (P[b] @ 1)  [P, C] bf16 (ones-MFMA
//      rowsum, fp8 1.0=0x38, layout-proof all-equal B frag).
//   6. out = wo @ h_at^T + bo + x  [C, B*P] fp32 == d_out layout
// QK/EXP/PV use bijective XCD swizzle; V/OUT keep default (already local).

typedef __bf16 bf16_t;
typedef __attribute__((ext_vector_type(4))) __bf16 bf16x4;
typedef __attribute__((ext_vector_type(8))) __bf16 bf16x8;
typedef __attribute__((ext_vector_type(4))) float floatx4;
typedef __attribute__((ext_vector_type(8))) int intx8;

constexpr int CDIM = 512;
constexpr int PDIM = 4096;

constexpr int ctz_c(int n) { return (n & 1) ? 0 : 1 + ctz_c(n >> 1); }

__device__ __forceinline__ void ld_g2l(const void* g, void* l) {
  __builtin_amdgcn_global_load_lds(
      (const __attribute__((address_space(1))) void*)g,
      (__attribute__((address_space(3))) void*)l,
      16, 0, 0);
}

__device__ __forceinline__ uint32_t pk_fp8x4(float a, float b, float c,
                                             float d) {
  int r = __builtin_amdgcn_cvt_pk_fp8_f32(a, b, 0, false);
  r = __builtin_amdgcn_cvt_pk_fp8_f32(c, d, r, true);
  return (uint32_t)r;
}

// two 16B LDS chunks -> one 8-reg MFMA fragment (SROA keeps it in regs)
__device__ __forceinline__ intx8 ld_frag(const uint8_t* base, int s0,
                                         int s1) {
  union {
    uint4 u[2];
    intx8 v;
  } r;
  r.u[0] = *(const uint4*)(base + s0);
  r.u[1] = *(const uint4*)(base + s1);
  return r.v;
}

// bijective row permutation for B staging: LDS row 16ni+fr holds global
// col 4fr+ni -> each lane's 4 ni-values are 4 consecutive columns.
__device__ __forceinline__ int sigma_row(int r) {
  return (r & 64) + ((r & 15) << 2) + ((r >> 4) & 3);
}

// bijective XCD-aware remap, compile-time pow2 grid -> pure shift/mask.
// Same mapping as round-3 runtime version (wg = (lin&7)*(nwg/8) + lin>>3).
template <int GX, int GY, int GZ>
__device__ __forceinline__ void xcd_remap(int& bx, int& by, int& bz) {
  constexpr int NWG = GX * GY * GZ;
  static_assert((NWG & 7) == 0 && (GX & (GX - 1)) == 0 &&
                    (GY & (GY - 1)) == 0,
                "pow2 grid, nwg%8==0");
  int lin = bx + GX * (by + GY * bz);
  int wg = (lin & 7) * (NWG >> 3) + (lin >> 3);
  bx = wg & (GX - 1);
  int t = wg >> ctz_c(GX);
  by = t & (GY - 1);
  bz = t >> ctz_c(GY);
}

enum { EPI_QK = 0, EPI_V = 1, EPI_OUT = 4, EPI_EXP = 2, EPI_PV = 5 };

// TN GEMM (bf16): C[M,N] = A[M,K] * B[N,K]^T, TMx128 tile, BK=64, NT thr,
// 16x16x32 MFMA, sigma-staged B + packed epilogue stores. K/strides are
// compile-time; K-loop fully unrolled (8 iters).
template <int EPI, int TM, int NT, bool SWZ, int K, int LDA, int LDB,
          int LDC, int GX = 1, int GY = 1, int GZ = 1>
__global__ __launch_bounds__(NT) void gemm_tn(
    const bf16_t* __restrict__ A, const bf16_t* __restrict__ B, long sAb,
    long sBb, long sCb, void* __restrict__ Cv,
    const float* __restrict__ bias, const float* __restrict__ xres) {
  constexpr int NW = NT / 64;
  constexpr int WROWS = TM / (NW / 2);
  constexpr int MI = WROWS / 16;
  constexpr int RB = NT / 8;    // rows staged per batch
  constexpr int AB = TM / RB;   // A stage batches
  constexpr int BB = 128 / RB;  // B stage batches
  constexpr int PMAX = AB > BB ? AB : BB;
  __shared__ bf16_t Asm[TM * 64];
  __shared__ bf16_t Bsm[128 * 64];

  const int tid = threadIdx.x;
  const int w = tid >> 6, l = tid & 63;
  int bx = blockIdx.x, by = blockIdx.y, bz = blockIdx.z;
  if constexpr (SWZ) xcd_remap<GX, GY, GZ>(bx, by, bz);
  const int m0 = by * TM, n0 = bx * 128;

  const bf16_t* Ab = A + (long)bz * sAb + (long)m0 * LDA;
  const bf16_t* Bb = B + (long)bz * sBb + (long)n0 * LDB;

  const int r0 = 8 * w + (l >> 3);
  const int schunk = (l & 7) ^ (l >> 3);
  const bf16_t* ga = Ab + (long)r0 * LDA + schunk * 8;
  const bf16_t* gb = Bb + schunk * 8;
  bf16_t* lA = Asm + (8 * w) * 64;
  bf16_t* lB = Bsm + (8 * w) * 64;

  const int wr = w >> 1, wc = w & 1;
  const int fr = l & 15, fq = l >> 4, l7 = l & 7;

  floatx4 acc[MI][4];
  floatx4 zz = {0.f, 0.f, 0.f, 0.f};
#pragma unroll
  for (int i = 0; i < MI; i++)
#pragma unroll
    for (int j = 0; j < 4; j++) acc[i][j] = zz;

#pragma unroll 8
  for (int it = 0; it < K / 64; it++) {
    const int kb = it * 64;
#pragma unroll
    for (int p = 0; p < PMAX; p++) {
      if (p < AB) ld_g2l(ga + (long)(p * RB) * LDA + kb, lA + p * RB * 64);
      if (p < BB) {
        const int sig = sigma_row(r0 + RB * p);  // B rows sigma-permuted
        ld_g2l(gb + (long)sig * LDB + kb, lB + p * RB * 64);
      }
    }
    __syncthreads();
#pragma unroll
    for (int ks = 0; ks < 2; ks++) {
      bf16x8 af[MI], bfv[4];
      const int ch = (ks * 4 + fq);
#pragma unroll
      for (int mi = 0; mi < MI; mi++) {
        int row = wr * WROWS + mi * 16 + fr;
        af[mi] = *(const bf16x8*)(Asm + row * 64 + ((ch ^ l7) * 8));
      }
#pragma unroll
      for (int ni = 0; ni < 4; ni++) {
        int row = wc * 64 + ni * 16 + fr;  // row&7 == l7
        bfv[ni] = *(const bf16x8*)(Bsm + row * 64 + ((ch ^ l7) * 8));
      }
#pragma unroll
      for (int mi = 0; mi < MI; mi++)
#pragma unroll
        for (int ni = 0; ni < 4; ni++)
          acc[mi][ni] = __builtin_amdgcn_mfma_f32_16x16x32_bf16(
              af[mi], bfv[ni], acc[mi][ni], 0, 0, 0);
    }
    __syncthreads();
  }

  // epilogue: sigma staging => MFMA ni, lane fr holds global col 4fr+ni
  const int rb = fq * 4;
  const int gcolb = n0 + wc * 64 + 4 * fr;
#pragma unroll
  for (int mi = 0; mi < MI; mi++) {
#pragma unroll
    for (int i = 0; i < 4; i++) {
      const int grow = m0 + wr * WROWS + mi * 16 + rb + i;
      float v0 = acc[mi][0][i], v1 = acc[mi][1][i];
      float v2 = acc[mi][2][i], v3 = acc[mi][3][i];
      if constexpr (EPI == EPI_QK) {
        // fp8 q||k output (q side pre-scaled via weights)
        const float4 b4 = *(const float4*)(bias + gcolb);
        *(uint32_t*)((uint8_t*)Cv + (long)bz * sCb + (long)grow * LDC +
                     gcolb) =
            pk_fp8x4(v0 + b4.x, v1 + b4.y, v2 + b4.z, v3 + b4.w);
      } else if constexpr (EPI == EPI_V) {
        const float bb = bias[grow];
        uint32_t d = pk_fp8x4(v0 + bb, v1 + bb, v2 + bb, v3 + bb);
        *(uint32_t*)((uint8_t*)Cv + (long)bz * sCb + (long)grow * LDC +
                     gcolb) = d;
      } else {  // EPI_OUT: grow = out channel, gcolb = b*P+p (4-aligned)
        int ob = gcolb >> 12, op = gcolb & 4095;
        long o = ((long)ob * CDIM + grow) * PDIM + op;
        const float4 xr = *(const float4*)(xres + o);
        const float bb = bias[grow];
        float4 ov = {v0 + bb + xr.x, v1 + bb + xr.y, v2 + bb + xr.z,
                     v3 + bb + xr.w};
        *(float4*)((float*)Cv + o) = ov;
      }
    }
  }
}

// fp8 TN GEMM via MX-scaled MFMA: C[M,N] op( A[M,K] * B[N,K]^T * 2^(SA-127) )
// TMx128 tile, BK=128, NT thr, mfma_scale_f32_16x16x128_f8f6f4.
// EPI_EXP: C = fp8(exp2(acc)). EPI_PV: C = bf16(acc / (P@1)) via ones-MFMA.
// K/strides compile-time; K-loop unroll 4 (EXP: full, PV: grouped).
template <int EPI, int TM, int SA, int NT, int K, int LDA, int LDB, int LDC,
          int GX, int GY, int GZ>
__global__ __launch_bounds__(NT) void gemm_f8(
    const uint8_t* __restrict__ A, const uint8_t* __restrict__ B, long sAb,
    long sBb, long sCb, void* __restrict__ Cv) {
  constexpr int NW = NT / 64;
  constexpr int WROWS = TM / (NW / 2);
  constexpr int MI = WROWS / 16;
  constexpr int RB = NT / 8;
  constexpr int AB = TM / RB;
  constexpr int BB = 128 / RB;
  constexpr int PMAX = AB > BB ? AB : BB;
  __shared__ uint8_t Asm[TM * 128];
  __shared__ uint8_t Bsm[128 * 128];

  const int tid = threadIdx.x;
  const int w = tid >> 6, l = tid & 63;
  int bx = blockIdx.x, by = blockIdx.y, bz = blockIdx.z;
  xcd_remap<GX, GY, GZ>(bx, by, bz);
  const int m0 = by * TM, n0 = bx * 128;

  const uint8_t* Ab = A + (long)bz * sAb + (long)m0 * LDA;
  const uint8_t* Bb = B + (long)bz * sBb + (long)n0 * LDB;

  const int r0 = 8 * w + (l >> 3);
  const int schunk = (l & 7) ^ (l >> 3);
  const uint8_t* ga = Ab + (long)r0 * LDA + schunk * 16;
  const uint8_t* gb = Bb + schunk * 16;
  uint8_t* lA = Asm + (8 * w) * 128;
  uint8_t* lB = Bsm + (8 * w) * 128;

  const int wr = w >> 1, wc = w & 1;
  const int fr = l & 15, fq = l >> 4, l7 = l & 7;

  floatx4 acc[MI][4];
  floatx4 accr[MI];  // PV row sums (P @ ones)
#pragma unroll
  for (int i = 0; i < MI; i++) {
#pragma unroll
    for (int j = 0; j < 4; j++) acc[i][j] = floatx4{0.f, 0.f, 0.f, 0.f};
    accr[i] = floatx4{0.f, 0.f, 0.f, 0.f};
  }

  const int s0 = ((2 * fq) ^ l7) * 16;
  const int s1 = ((2 * fq + 1) ^ l7) * 16;

#pragma unroll 4
  for (int it = 0; it < K / 128; it++) {
    const int kb = it * 128;
#pragma unroll
    for (int p = 0; p < PMAX; p++) {
      if (p < AB) ld_g2l(ga + (long)(p * RB) * LDA + kb, lA + p * RB * 128);
      if (p < BB) {
        const int sig = sigma_row(r0 + RB * p);  // B rows sigma-permuted
        ld_g2l(gb + (long)sig * LDB + kb, lB + p * RB * 128);
      }
    }
    __syncthreads();

    intx8 af[MI];
#pragma unroll
    for (int mi = 0; mi < MI; mi++)
      af[mi] = ld_frag(Asm + (wr * WROWS + mi * 16 + fr) * 128, s0, s1);
#pragma unroll
    for (int ni = 0; ni < 4; ni++) {
      // row&7 == l7 -> conflict-free
      intx8 bf = ld_frag(Bsm + (wc * 64 + ni * 16 + fr) * 128, s0, s1);
#pragma unroll
      for (int mi = 0; mi < MI; mi++)
        acc[mi][ni] = __builtin_amdgcn_mfma_scale_f32_16x16x128_f8f6f4(
            af[mi], bf, acc[mi][ni], 0, 0, 0, SA, 0, 127);
    }
    if constexpr (EPI == EPI_PV) {
      const int one8 = 0x38383838;  // 4x fp8 e4m3 1.0
      const intx8 ones = {one8, one8, one8, one8, one8, one8, one8, one8};
#pragma unroll
      for (int mi = 0; mi < MI; mi++)
        accr[mi] = __builtin_amdgcn_mfma_scale_f32_16x16x128_f8f6f4(
            af[mi], ones, accr[mi], 0, 0, 0, SA, 0, 127);
    }
    __syncthreads();
  }

  const int rb = fq * 4;
  const int gcolb = n0 + wc * 64 + 4 * fr;
#pragma unroll
  for (int mi = 0; mi < MI; mi++) {
#pragma unroll
    for (int i = 0; i < 4; i++) {
      const int grow = m0 + wr * WROWS + mi * 16 + rb + i;
      if constexpr (EPI == EPI_EXP) {
        // acc already in log2 units (weight prescale + 2^-4 MX scale)
        float p0 = exp2f(acc[mi][0][i]), p1 = exp2f(acc[mi][1][i]);
        float p2 = exp2f(acc[mi][2][i]), p3 = exp2f(acc[mi][3][i]);
        *(uint32_t*)((uint8_t*)Cv + (long)bz * sCb + (long)grow * LDC +
                     gcolb) = pk_fp8x4(p0, p1, p2, p3);
      } else {  // EPI_PV: every column of accr == rowsum for this row
        const float inv = __builtin_amdgcn_rcpf(accr[mi][i]);
        bf16x4 o = {(bf16_t)(acc[mi][0][i] * inv),
                    (bf16_t)(acc[mi][1][i] * inv),
                    (bf16_t)(acc[mi][2][i] * inv),
                    (bf16_t)(acc[mi][3][i] * inv)};
        *(bf16x4*)((bf16_t*)Cv + (long)bz * sCb + (long)grow * LDC + gcolb) =
            o;
      }
    }
  }
}

// Stage 1: partial sums. Block i reads x[i*8192 .. +8192), writes (sum, sumsq).
__global__ __launch_bounds__(256) void gn_stats(const float* __restrict__ x,
                                                float2* __restrict__ part) {
  const int i = blockIdx.x;
  const float4* xp = (const float4*)(x + (long)i * 8192);
  float s0 = 0.f, s1 = 0.f;
  for (int j = threadIdx.x; j < 2048; j += 256) {
    float4 v = xp[j];
    s0 += v.x + v.y + v.z + v.w;
    s1 += v.x * v.x + v.y * v.y + v.z * v.z + v.w * v.w;
  }
  for (int o = 32; o; o >>= 1) {
    s0 += __shfl_xor(s0, o);
    s1 += __shfl_xor(s1, o);
  }
  __shared__ float r0[4], r1[4];
  if ((threadIdx.x & 63) == 0) {
    r0[threadIdx.x >> 6] = s0;
    r1[threadIdx.x >> 6] = s1;
  }
  __syncthreads();
  if (threadIdx.x == 0)
    part[i] = make_float2(r0[0] + r0[1] + r0[2] + r0[3],
                          r1[0] + r1[1] + r1[2] + r1[3]);
}

// Stage 2: normalize + transpose via LDS tile. Block = (b, 32 p-rows).
__global__ __launch_bounds__(256) void gn_norm(
    const float* __restrict__ x, const float* __restrict__ gamma,
    const float* __restrict__ beta, const float2* __restrict__ part,
    bf16_t* __restrict__ h_t) {
  const int b = blockIdx.x >> 7;
  const int p0 = (blockIdx.x & 127) * 32;
  const int t = threadIdx.x;
  __shared__ float gmS[512], btS[512];
  __shared__ float gmean[32], grstd[32];
  __shared__ __align__(16) bf16_t tile[32 * 520];

  if (t < 32) {
    const float2* pp = part + (b * 32 + t) * 8;
    float s0 = 0.f, s1 = 0.f;
#pragma unroll
    for (int s = 0; s < 8; s++) {
      float2 v = pp[s];
      s0 += v.x;
      s1 += v.y;
    }
    float mean = s0 * (1.f / 65536.f);
    float var = s1 * (1.f / 65536.f) - mean * mean;
    gmean[t] = mean;
    grstd[t] = rsqrtf(var + 1e-6f);
  }
  __syncthreads();
  for (int c = t; c < 512; c += 256) {
    float g = gamma[c] * grstd[c >> 4];
    gmS[c] = g;
    btS[c] = beta[c] - gmean[c >> 4] * g;
  }
  __syncthreads();

  const int cc = t >> 3, pcol = (t & 7) * 4;
  for (int pass = 0; pass < 16; pass++) {
    int c = pass * 32 + cc;
    float4 v = *(const float4*)(x + ((long)(b * 512 + c)) * 4096 + p0 + pcol);
    float g = gmS[c], bb = btS[c];
    tile[(pcol + 0) * 520 + c] = (bf16_t)(v.x * g + bb);
    tile[(pcol + 1) * 520 + c] = (bf16_t)(v.y * g + bb);
    tile[(pcol + 2) * 520 + c] = (bf16_t)(v.z * g + bb);
    tile[(pcol + 3) * 520 + c] = (bf16_t)(v.w * g + bb);
  }
  __syncthreads();
  const int p = t >> 3;
  bf16_t* orow = h_t + ((long)(b * 4096 + p0 + p)) * 512;
  const bf16_t* trow = tile + p * 520;
#pragma unroll
  for (int j = 0; j < 8; j++) {
    int ch = (t & 7) + 8 * j;
    *(uint4*)(orow + ch * 8) = *(const uint4*)(trow + ch * 8);
  }
}

// wq,bq prescaled by (log2e/sqrt(512)) / 2^-4 so the EXP GEMM's e8m0
// A-scale of 123 (2^-4) yields log2-domain scores directly.
__global__ __launch_bounds__(256) void cvt_weights(
    const float* __restrict__ wq, const float* __restrict__ wk,
    const float* __restrict__ wv, const float* __restrict__ wo,
    const float* __restrict__ bq, const float* __restrict__ bk,
    bf16_t* __restrict__ out, float* __restrict__ bqk) {
  constexpr float QW = 1.02013936f;  // (1/sqrt(512))*log2(e) / 2^-4
  int i = blockIdx.x * 256 + threadIdx.x;
  out[i] = (bf16_t)(wq[i] * QW);
  out[262144 + i] = (bf16_t)wk[i];
  out[2 * 262144 + i] = (bf16_t)wv[i];
  out[3 * 262144 + i] = (bf16_t)wo[i];
  if (i < 512)
    bqk[i] = bq[i] * QW;
  else if (i < 1024)
    bqk[i] = bk[i - 512];
}

extern "C" void kernel_launch(void* const* d_in, const int* in_sizes, int n_in,
                              void* d_out, int out_size, void* d_ws,
                              size_t ws_size, hipStream_t stream) {
  const float* x = (const float*)d_in[0];
  const float* gamma = (const float*)d_in[1];
  const float* beta = (const float*)d_in[2];
  const float* wq = (const float*)d_in[3];
  const float* bq = (const float*)d_in[4];
  const float* wk = (const float*)d_in[5];
  const float* bk = (const float*)d_in[6];
  const float* wv = (const float*)d_in[7];
  const float* bv = (const float*)d_in[8];
  const float* wo = (const float*)d_in[9];
  const float* bo = (const float*)d_in[10];

  char* ws = (char*)d_ws;
  bf16_t* h_t = (bf16_t*)(ws);                  // [16384,512] bf16  @0
  uint8_t* qk8 = (uint8_t*)(ws + (16l << 20));  // [16384,1024] fp8  @16MB
  uint8_t* v_c = (uint8_t*)(ws + (48l << 20));  // [512,16384] fp8   @48MB
  bf16_t* h_at = (bf16_t*)(ws + (64l << 20));   // [16384,512] bf16  @64MB
  bf16_t* w_b = (bf16_t*)(ws + (80l << 20));    // 4x[512,512] bf16  @80MB
  float2* part = (float2*)(ws + (83l << 20));   // [1024] partials   @83MB
  float* bqk = (float*)(ws + (83l << 20) + (64l << 10));  // [1024]
  uint8_t* Sbuf = (uint8_t*)(ws + (84l << 20)); // [4,4096,4096] fp8 @84MB

  const long sQK8 = (long)PDIM * 1024;  // bytes per batch of qk8
  const long sS = (long)PDIM * PDIM;    // 16777216

  cvt_weights<<<1024, 256, 0, stream>>>(wq, wk, wv, wo, bq, bk, w_b, bqk);
  gn_stats<<<1024, 256, 0, stream>>>(x, part);
  gn_norm<<<512, 256, 0, stream>>>(x, gamma, beta, part, h_t);
  // fused q|k projection -> fp8: B = [wq;wk] rows 0..1023, bias bqk
  gemm_tn<EPI_QK, 128, 256, true, 512, 512, 512, 1024, 8, 128, 1>
      <<<dim3(8, 128, 1), 256, 0, stream>>>(h_t, w_b, 0, 0, 0, qk8, bqk,
                                            nullptr);
  gemm_tn<EPI_V, 64, 256, false, 512, 512, 512, 16384>
      <<<dim3(128, 8, 1), 256, 0, stream>>>(w_b + 2 * 262144, h_t, 0, 0, 0,
                                            v_c, bv, nullptr);
  // P = exp2(2^-4 * q8 k8^T) fp8 (unnormalized; sums computed in PV)
  gemm_f8<EPI_EXP, 128, 123, 256, 512, 1024, 1024, 4096, 32, 32, 4>
      <<<dim3(32, 32, 4), 256, 0, stream>>>(qk8, qk8 + 512, sQK8, sQK8, sS,
                                            Sbuf);
  // h_at = (P @ v^T) / (P @ 1)  — MX-fp8 K=128 MFMA, rsum via ones-MFMA
  gemm_f8<EPI_PV, 128, 127, 256, 4096, 4096, 16384, 512, 4, 32, 4>
      <<<dim3(4, 32, 4), 256, 0, stream>>>(Sbuf, v_c, sS, 4096,
                                           (long)PDIM * CDIM, h_at);
  gemm_tn<EPI_OUT, 64, 256, false, 512, 512, 512, 4096>
      <<<dim3(128, 8, 1), 256, 0, stream>>>(w_b + 3 * 262144, h_at, 0, 0, 0,
                                            d_out, bo, x);
}

// Round 5
// 254.169 us; speedup vs baseline: 1.1991x; 1.0150x over previous
//
#include <hip/hip_runtime.h>
#include <stdint.h>

// SpatialSelfAttention: B=4, C=512, P=4096, 32 groups.
// Pipeline (round 12: round-11 const-prop KEPT, f8 K-loop unroll pinned to 1):
//   Round-4 postmortem: #pragma unroll 4 on gemm_f8's K-loop hoisted all
//   staging addresses -> VGPR 76->88, occupancy 27.7->20.5%, EXP 54.7->64.5us
//   (this 4-iter 2-barrier kernel lives on TLP to hide the vmcnt(0)+barrier
//   drains). The const-strides/shift-mask-remap part was a clear win for the
//   other GEMMs (-15us). Keep const-prop, pin unroll 1 -> round-3 codegen
//   shape with round-4 addressing cost.
//   1. cvt weights fp32->bf16 (wq,bq prescaled by 1.02014 = qscale2/2^-4)
//   2. gn_stats + gn_norm -> h_t [B*P, C] bf16 (LDS tile transpose)
//   3. qk8 = h_t @ [wq;wk]^T  [B*P, 1024] fp8 e4m3
//      v_c = wv @ h_t^T       [C, B*P]  fp8 e4m3
//   4. P[b] = exp2(2^-4 * q8[b] @ k8[b]^T)  [P,P] fp8 via MX-scaled
//      mfma_scale_f32_16x16x128_f8f6f4 (A-scale e8m0=123 -> 2^-4).
//   5. h_at[b] = (P[b] @ v_c[b]^T) / (P[b] @ 1)  [P, C] bf16 (ones-MFMA
//      rowsum, fp8 1.0=0x38, layout-proof all-equal B frag).
//   6. out = wo @ h_at^T + bo + x  [C, B*P] fp32 == d_out layout
// QK/EXP/PV use bijective XCD swizzle; V/OUT keep default (already local).

typedef __bf16 bf16_t;
typedef __attribute__((ext_vector_type(4))) __bf16 bf16x4;
typedef __attribute__((ext_vector_type(8))) __bf16 bf16x8;
typedef __attribute__((ext_vector_type(4))) float floatx4;
typedef __attribute__((ext_vector_type(8))) int intx8;

constexpr int CDIM = 512;
constexpr int PDIM = 4096;

constexpr int ctz_c(int n) { return (n & 1) ? 0 : 1 + ctz_c(n >> 1); }

__device__ __forceinline__ void ld_g2l(const void* g, void* l) {
  __builtin_amdgcn_global_load_lds(
      (const __attribute__((address_space(1))) void*)g,
      (__attribute__((address_space(3))) void*)l,
      16, 0, 0);
}

__device__ __forceinline__ uint32_t pk_fp8x4(float a, float b, float c,
                                             float d) {
  int r = __builtin_amdgcn_cvt_pk_fp8_f32(a, b, 0, false);
  r = __builtin_amdgcn_cvt_pk_fp8_f32(c, d, r, true);
  return (uint32_t)r;
}

// two 16B LDS chunks -> one 8-reg MFMA fragment (SROA keeps it in regs)
__device__ __forceinline__ intx8 ld_frag(const uint8_t* base, int s0,
                                         int s1) {
  union {
    uint4 u[2];
    intx8 v;
  } r;
  r.u[0] = *(const uint4*)(base + s0);
  r.u[1] = *(const uint4*)(base + s1);
  return r.v;
}

// bijective row permutation for B staging: LDS row 16ni+fr holds global
// col 4fr+ni -> each lane's 4 ni-values are 4 consecutive columns.
__device__ __forceinline__ int sigma_row(int r) {
  return (r & 64) + ((r & 15) << 2) + ((r >> 4) & 3);
}

// bijective XCD-aware remap, compile-time pow2 grid -> pure shift/mask.
template <int GX, int GY, int GZ>
__device__ __forceinline__ void xcd_remap(int& bx, int& by, int& bz) {
  constexpr int NWG = GX * GY * GZ;
  static_assert((NWG & 7) == 0 && (GX & (GX - 1)) == 0 &&
                    (GY & (GY - 1)) == 0,
                "pow2 grid, nwg%8==0");
  int lin = bx + GX * (by + GY * bz);
  int wg = (lin & 7) * (NWG >> 3) + (lin >> 3);
  bx = wg & (GX - 1);
  int t = wg >> ctz_c(GX);
  by = t & (GY - 1);
  bz = t >> ctz_c(GY);
}

enum { EPI_QK = 0, EPI_V = 1, EPI_OUT = 4, EPI_EXP = 2, EPI_PV = 5 };

// TN GEMM (bf16): C[M,N] = A[M,K] * B[N,K]^T, TMx128 tile, BK=64, NT thr,
// 16x16x32 MFMA, sigma-staged B + packed epilogue stores. K/strides are
// compile-time; K-loop fully unrolled (8 iters).
template <int EPI, int TM, int NT, bool SWZ, int K, int LDA, int LDB,
          int LDC, int GX = 1, int GY = 1, int GZ = 1>
__global__ __launch_bounds__(NT) void gemm_tn(
    const bf16_t* __restrict__ A, const bf16_t* __restrict__ B, long sAb,
    long sBb, long sCb, void* __restrict__ Cv,
    const float* __restrict__ bias, const float* __restrict__ xres) {
  constexpr int NW = NT / 64;
  constexpr int WROWS = TM / (NW / 2);
  constexpr int MI = WROWS / 16;
  constexpr int RB = NT / 8;    // rows staged per batch
  constexpr int AB = TM / RB;   // A stage batches
  constexpr int BB = 128 / RB;  // B stage batches
  constexpr int PMAX = AB > BB ? AB : BB;
  __shared__ bf16_t Asm[TM * 64];
  __shared__ bf16_t Bsm[128 * 64];

  const int tid = threadIdx.x;
  const int w = tid >> 6, l = tid & 63;
  int bx = blockIdx.x, by = blockIdx.y, bz = blockIdx.z;
  if constexpr (SWZ) xcd_remap<GX, GY, GZ>(bx, by, bz);
  const int m0 = by * TM, n0 = bx * 128;

  const bf16_t* Ab = A + (long)bz * sAb + (long)m0 * LDA;
  const bf16_t* Bb = B + (long)bz * sBb + (long)n0 * LDB;

  const int r0 = 8 * w + (l >> 3);
  const int schunk = (l & 7) ^ (l >> 3);
  const bf16_t* ga = Ab + (long)r0 * LDA + schunk * 8;
  const bf16_t* gb = Bb + schunk * 8;
  bf16_t* lA = Asm + (8 * w) * 64;
  bf16_t* lB = Bsm + (8 * w) * 64;

  const int wr = w >> 1, wc = w & 1;
  const int fr = l & 15, fq = l >> 4, l7 = l & 7;

  floatx4 acc[MI][4];
  floatx4 zz = {0.f, 0.f, 0.f, 0.f};
#pragma unroll
  for (int i = 0; i < MI; i++)
#pragma unroll
    for (int j = 0; j < 4; j++) acc[i][j] = zz;

#pragma unroll 8
  for (int it = 0; it < K / 64; it++) {
    const int kb = it * 64;
#pragma unroll
    for (int p = 0; p < PMAX; p++) {
      if (p < AB) ld_g2l(ga + (long)(p * RB) * LDA + kb, lA + p * RB * 64);
      if (p < BB) {
        const int sig = sigma_row(r0 + RB * p);  // B rows sigma-permuted
        ld_g2l(gb + (long)sig * LDB + kb, lB + p * RB * 64);
      }
    }
    __syncthreads();
#pragma unroll
    for (int ks = 0; ks < 2; ks++) {
      bf16x8 af[MI], bfv[4];
      const int ch = (ks * 4 + fq);
#pragma unroll
      for (int mi = 0; mi < MI; mi++) {
        int row = wr * WROWS + mi * 16 + fr;
        af[mi] = *(const bf16x8*)(Asm + row * 64 + ((ch ^ l7) * 8));
      }
#pragma unroll
      for (int ni = 0; ni < 4; ni++) {
        int row = wc * 64 + ni * 16 + fr;  // row&7 == l7
        bfv[ni] = *(const bf16x8*)(Bsm + row * 64 + ((ch ^ l7) * 8));
      }
#pragma unroll
      for (int mi = 0; mi < MI; mi++)
#pragma unroll
        for (int ni = 0; ni < 4; ni++)
          acc[mi][ni] = __builtin_amdgcn_mfma_f32_16x16x32_bf16(
              af[mi], bfv[ni], acc[mi][ni], 0, 0, 0);
    }
    __syncthreads();
  }

  // epilogue: sigma staging => MFMA ni, lane fr holds global col 4fr+ni
  const int rb = fq * 4;
  const int gcolb = n0 + wc * 64 + 4 * fr;
#pragma unroll
  for (int mi = 0; mi < MI; mi++) {
#pragma unroll
    for (int i = 0; i < 4; i++) {
      const int grow = m0 + wr * WROWS + mi * 16 + rb + i;
      float v0 = acc[mi][0][i], v1 = acc[mi][1][i];
      float v2 = acc[mi][2][i], v3 = acc[mi][3][i];
      if constexpr (EPI == EPI_QK) {
        // fp8 q||k output (q side pre-scaled via weights)
        const float4 b4 = *(const float4*)(bias + gcolb);
        *(uint32_t*)((uint8_t*)Cv + (long)bz * sCb + (long)grow * LDC +
                     gcolb) =
            pk_fp8x4(v0 + b4.x, v1 + b4.y, v2 + b4.z, v3 + b4.w);
      } else if constexpr (EPI == EPI_V) {
        const float bb = bias[grow];
        uint32_t d = pk_fp8x4(v0 + bb, v1 + bb, v2 + bb, v3 + bb);
        *(uint32_t*)((uint8_t*)Cv + (long)bz * sCb + (long)grow * LDC +
                     gcolb) = d;
      } else {  // EPI_OUT: grow = out channel, gcolb = b*P+p (4-aligned)
        int ob = gcolb >> 12, op = gcolb & 4095;
        long o = ((long)ob * CDIM + grow) * PDIM + op;
        const float4 xr = *(const float4*)(xres + o);
        const float bb = bias[grow];
        float4 ov = {v0 + bb + xr.x, v1 + bb + xr.y, v2 + bb + xr.z,
                     v3 + bb + xr.w};
        *(float4*)((float*)Cv + o) = ov;
      }
    }
  }
}

// fp8 TN GEMM via MX-scaled MFMA: C[M,N] op( A[M,K] * B[N,K]^T * 2^(SA-127) )
// TMx128 tile, BK=128, NT thr, mfma_scale_f32_16x16x128_f8f6f4.
// EPI_EXP: C = fp8(exp2(acc)). EPI_PV: C = bf16(acc / (P@1)) via ones-MFMA.
// K/strides compile-time; K-loop unroll PINNED to 1 (unroll 4 cost 10us in
// EXP via VGPR 76->88 occupancy drop — round-4 postmortem).
template <int EPI, int TM, int SA, int NT, int K, int LDA, int LDB, int LDC,
          int GX, int GY, int GZ>
__global__ __launch_bounds__(NT) void gemm_f8(
    const uint8_t* __restrict__ A, const uint8_t* __restrict__ B, long sAb,
    long sBb, long sCb, void* __restrict__ Cv) {
  constexpr int NW = NT / 64;
  constexpr int WROWS = TM / (NW / 2);
  constexpr int MI = WROWS / 16;
  constexpr int RB = NT / 8;
  constexpr int AB = TM / RB;
  constexpr int BB = 128 / RB;
  constexpr int PMAX = AB > BB ? AB : BB;
  __shared__ uint8_t Asm[TM * 128];
  __shared__ uint8_t Bsm[128 * 128];

  const int tid = threadIdx.x;
  const int w = tid >> 6, l = tid & 63;
  int bx = blockIdx.x, by = blockIdx.y, bz = blockIdx.z;
  xcd_remap<GX, GY, GZ>(bx, by, bz);
  const int m0 = by * TM, n0 = bx * 128;

  const uint8_t* Ab = A + (long)bz * sAb + (long)m0 * LDA;
  const uint8_t* Bb = B + (long)bz * sBb + (long)n0 * LDB;

  const int r0 = 8 * w + (l >> 3);
  const int schunk = (l & 7) ^ (l >> 3);
  const uint8_t* ga = Ab + (long)r0 * LDA + schunk * 16;
  const uint8_t* gb = Bb + schunk * 16;
  uint8_t* lA = Asm + (8 * w) * 128;
  uint8_t* lB = Bsm + (8 * w) * 128;

  const int wr = w >> 1, wc = w & 1;
  const int fr = l & 15, fq = l >> 4, l7 = l & 7;

  floatx4 acc[MI][4];
  floatx4 accr[MI];  // PV row sums (P @ ones)
#pragma unroll
  for (int i = 0; i < MI; i++) {
#pragma unroll
    for (int j = 0; j < 4; j++) acc[i][j] = floatx4{0.f, 0.f, 0.f, 0.f};
    accr[i] = floatx4{0.f, 0.f, 0.f, 0.f};
  }

  const int s0 = ((2 * fq) ^ l7) * 16;
  const int s1 = ((2 * fq + 1) ^ l7) * 16;

#pragma unroll 1
  for (int it = 0; it < K / 128; it++) {
    const int kb = it * 128;
#pragma unroll
    for (int p = 0; p < PMAX; p++) {
      if (p < AB) ld_g2l(ga + (long)(p * RB) * LDA + kb, lA + p * RB * 128);
      if (p < BB) {
        const int sig = sigma_row(r0 + RB * p);  // B rows sigma-permuted
        ld_g2l(gb + (long)sig * LDB + kb, lB + p * RB * 128);
      }
    }
    __syncthreads();

    intx8 af[MI];
#pragma unroll
    for (int mi = 0; mi < MI; mi++)
      af[mi] = ld_frag(Asm + (wr * WROWS + mi * 16 + fr) * 128, s0, s1);
#pragma unroll
    for (int ni = 0; ni < 4; ni++) {
      // row&7 == l7 -> conflict-free
      intx8 bf = ld_frag(Bsm + (wc * 64 + ni * 16 + fr) * 128, s0, s1);
#pragma unroll
      for (int mi = 0; mi < MI; mi++)
        acc[mi][ni] = __builtin_amdgcn_mfma_scale_f32_16x16x128_f8f6f4(
            af[mi], bf, acc[mi][ni], 0, 0, 0, SA, 0, 127);
    }
    if constexpr (EPI == EPI_PV) {
      const int one8 = 0x38383838;  // 4x fp8 e4m3 1.0
      const intx8 ones = {one8, one8, one8, one8, one8, one8, one8, one8};
#pragma unroll
      for (int mi = 0; mi < MI; mi++)
        accr[mi] = __builtin_amdgcn_mfma_scale_f32_16x16x128_f8f6f4(
            af[mi], ones, accr[mi], 0, 0, 0, SA, 0, 127);
    }
    __syncthreads();
  }

  const int rb = fq * 4;
  const int gcolb = n0 + wc * 64 + 4 * fr;
#pragma unroll
  for (int mi = 0; mi < MI; mi++) {
#pragma unroll
    for (int i = 0; i < 4; i++) {
      const int grow = m0 + wr * WROWS + mi * 16 + rb + i;
      if constexpr (EPI == EPI_EXP) {
        // acc already in log2 units (weight prescale + 2^-4 MX scale)
        float p0 = exp2f(acc[mi][0][i]), p1 = exp2f(acc[mi][1][i]);
        float p2 = exp2f(acc[mi][2][i]), p3 = exp2f(acc[mi][3][i]);
        *(uint32_t*)((uint8_t*)Cv + (long)bz * sCb + (long)grow * LDC +
                     gcolb) = pk_fp8x4(p0, p1, p2, p3);
      } else {  // EPI_PV: every column of accr == rowsum for this row
        const float inv = __builtin_amdgcn_rcpf(accr[mi][i]);
        bf16x4 o = {(bf16_t)(acc[mi][0][i] * inv),
                    (bf16_t)(acc[mi][1][i] * inv),
                    (bf16_t)(acc[mi][2][i] * inv),
                    (bf16_t)(acc[mi][3][i] * inv)};
        *(bf16x4*)((bf16_t*)Cv + (long)bz * sCb + (long)grow * LDC + gcolb) =
            o;
      }
    }
  }
}

// Stage 1: partial sums. Block i reads x[i*8192 .. +8192), writes (sum, sumsq).
__global__ __launch_bounds__(256) void gn_stats(const float* __restrict__ x,
                                                float2* __restrict__ part) {
  const int i = blockIdx.x;
  const float4* xp = (const float4*)(x + (long)i * 8192);
  float s0 = 0.f, s1 = 0.f;
  for (int j = threadIdx.x; j < 2048; j += 256) {
    float4 v = xp[j];
    s0 += v.x + v.y + v.z + v.w;
    s1 += v.x * v.x + v.y * v.y + v.z * v.z + v.w * v.w;
  }
  for (int o = 32; o; o >>= 1) {
    s0 += __shfl_xor(s0, o);
    s1 += __shfl_xor(s1, o);
  }
  __shared__ float r0[4], r1[4];
  if ((threadIdx.x & 63) == 0) {
    r0[threadIdx.x >> 6] = s0;
    r1[threadIdx.x >> 6] = s1;
  }
  __syncthreads();
  if (threadIdx.x == 0)
    part[i] = make_float2(r0[0] + r0[1] + r0[2] + r0[3],
                          r1[0] + r1[1] + r1[2] + r1[3]);
}

// Stage 2: normalize + transpose via LDS tile. Block = (b, 32 p-rows).
__global__ __launch_bounds__(256) void gn_norm(
    const float* __restrict__ x, const float* __restrict__ gamma,
    const float* __restrict__ beta, const float2* __restrict__ part,
    bf16_t* __restrict__ h_t) {
  const int b = blockIdx.x >> 7;
  const int p0 = (blockIdx.x & 127) * 32;
  const int t = threadIdx.x;
  __shared__ float gmS[512], btS[512];
  __shared__ float gmean[32], grstd[32];
  __shared__ __align__(16) bf16_t tile[32 * 520];

  if (t < 32) {
    const float2* pp = part + (b * 32 + t) * 8;
    float s0 = 0.f, s1 = 0.f;
#pragma unroll
    for (int s = 0; s < 8; s++) {
      float2 v = pp[s];
      s0 += v.x;
      s1 += v.y;
    }
    float mean = s0 * (1.f / 65536.f);
    float var = s1 * (1.f / 65536.f) - mean * mean;
    gmean[t] = mean;
    grstd[t] = rsqrtf(var + 1e-6f);
  }
  __syncthreads();
  for (int c = t; c < 512; c += 256) {
    float g = gamma[c] * grstd[c >> 4];
    gmS[c] = g;
    btS[c] = beta[c] - gmean[c >> 4] * g;
  }
  __syncthreads();

  const int cc = t >> 3, pcol = (t & 7) * 4;
  for (int pass = 0; pass < 16; pass++) {
    int c = pass * 32 + cc;
    float4 v = *(const float4*)(x + ((long)(b * 512 + c)) * 4096 + p0 + pcol);
    float g = gmS[c], bb = btS[c];
    tile[(pcol + 0) * 520 + c] = (bf16_t)(v.x * g + bb);
    tile[(pcol + 1) * 520 + c] = (bf16_t)(v.y * g + bb);
    tile[(pcol + 2) * 520 + c] = (bf16_t)(v.z * g + bb);
    tile[(pcol + 3) * 520 + c] = (bf16_t)(v.w * g + bb);
  }
  __syncthreads();
  const int p = t >> 3;
  bf16_t* orow = h_t + ((long)(b * 4096 + p0 + p)) * 512;
  const bf16_t* trow = tile + p * 520;
#pragma unroll
  for (int j = 0; j < 8; j++) {
    int ch = (t & 7) + 8 * j;
    *(uint4*)(orow + ch * 8) = *(const uint4*)(trow + ch * 8);
  }
}

// wq,bq prescaled by (log2e/sqrt(512)) / 2^-4 so the EXP GEMM's e8m0
// A-scale of 123 (2^-4) yields log2-domain scores directly.
__global__ __launch_bounds__(256) void cvt_weights(
    const float* __restrict__ wq, const float* __restrict__ wk,
    const float* __restrict__ wv, const float* __restrict__ wo,
    const float* __restrict__ bq, const float* __restrict__ bk,
    bf16_t* __restrict__ out, float* __restrict__ bqk) {
  constexpr float QW = 1.02013936f;  // (1/sqrt(512))*log2(e) / 2^-4
  int i = blockIdx.x * 256 + threadIdx.x;
  out[i] = (bf16_t)(wq[i] * QW);
  out[262144 + i] = (bf16_t)wk[i];
  out[2 * 262144 + i] = (bf16_t)wv[i];
  out[3 * 262144 + i] = (bf16_t)wo[i];
  if (i < 512)
    bqk[i] = bq[i] * QW;
  else if (i < 1024)
    bqk[i] = bk[i - 512];
}

extern "C" void kernel_launch(void* const* d_in, const int* in_sizes, int n_in,
                              void* d_out, int out_size, void* d_ws,
                              size_t ws_size, hipStream_t stream) {
  const float* x = (const float*)d_in[0];
  const float* gamma = (const float*)d_in[1];
  const float* beta = (const float*)d_in[2];
  const float* wq = (const float*)d_in[3];
  const float* bq = (const float*)d_in[4];
  const float* wk = (const float*)d_in[5];
  const float* bk = (const float*)d_in[6];
  const float* wv = (const float*)d_in[7];
  const float* bv = (const float*)d_in[8];
  const float* wo = (const float*)d_in[9];
  const float* bo = (const float*)d_in[10];

  char* ws = (char*)d_ws;
  bf16_t* h_t = (bf16_t*)(ws);                  // [16384,512] bf16  @0
  uint8_t* qk8 = (uint8_t*)(ws + (16l << 20));  // [16384,1024] fp8  @16MB
  uint8_t* v_c = (uint8_t*)(ws + (48l << 20));  // [512,16384] fp8   @48MB
  bf16_t* h_at = (bf16_t*)(ws + (64l << 20));   // [16384,512] bf16  @64MB
  bf16_t* w_b = (bf16_t*)(ws + (80l << 20));    // 4x[512,512] bf16  @80MB
  float2* part = (float2*)(ws + (83l << 20));   // [1024] partials   @83MB
  float* bqk = (float*)(ws + (83l << 20) + (64l << 10));  // [1024]
  uint8_t* Sbuf = (uint8_t*)(ws + (84l << 20)); // [4,4096,4096] fp8 @84MB

  const long sQK8 = (long)PDIM * 1024;  // bytes per batch of qk8
  const long sS = (long)PDIM * PDIM;    // 16777216

  cvt_weights<<<1024, 256, 0, stream>>>(wq, wk, wv, wo, bq, bk, w_b, bqk);
  gn_stats<<<1024, 256, 0, stream>>>(x, part);
  gn_norm<<<512, 256, 0, stream>>>(x, gamma, beta, part, h_t);
  // fused q|k projection -> fp8: B = [wq;wk] rows 0..1023, bias bqk
  gemm_tn<EPI_QK, 128, 256, true, 512, 512, 512, 1024, 8, 128, 1>
      <<<dim3(8, 128, 1), 256, 0, stream>>>(h_t, w_b, 0, 0, 0, qk8, bqk,
                                            nullptr);
  gemm_tn<EPI_V, 64, 256, false, 512, 512, 512, 16384>
      <<<dim3(128, 8, 1), 256, 0, stream>>>(w_b + 2 * 262144, h_t, 0, 0, 0,
                                            v_c, bv, nullptr);
  // P = exp2(2^-4 * q8 k8^T) fp8 (unnormalized; sums computed in PV)
  gemm_f8<EPI_EXP, 128, 123, 256, 512, 1024, 1024, 4096, 32, 32, 4>
      <<<dim3(32, 32, 4), 256, 0, stream>>>(qk8, qk8 + 512, sQK8, sQK8, sS,
                                            Sbuf);
  // h_at = (P @ v^T) / (P @ 1)  — MX-fp8 K=128 MFMA, rsum via ones-MFMA
  gemm_f8<EPI_PV, 128, 127, 256, 4096, 4096, 16384, 512, 4, 32, 4>
      <<<dim3(4, 32, 4), 256, 0, stream>>>(Sbuf, v_c, sS, 4096,
                                           (long)PDIM * CDIM, h_at);
  gemm_tn<EPI_OUT, 64, 256, false, 512, 512, 512, 4096>
      <<<dim3(128, 8, 1), 256, 0, stream>>>(w_b + 3 * 262144, h_at, 0, 0, 0,
                                            d_out, bo, x);
}

// Round 6
// 249.597 us; speedup vs baseline: 1.2211x; 1.0183x over previous
//
#include <hip/hip_runtime.h>
#include <stdint.h>

// SpatialSelfAttention: B=4, C=512, P=4096, 32 groups.
// Pipeline (round 13: T3 2-phase double-buffer in gemm_f8):
//   Round-5 ledger: EXP 51.7us + PV ~48us dominate; both latency-bound
//   (MfmaUtil 26%, VALUBusy 52%, occ 27%) on the 2-barrier serial
//   stage->vmcnt(0)->compute K-loop. Fix: LDS ping-pong double-buffer,
//   issue next-tile global_load_lds BEFORE computing current tile, ONE
//   __syncthreads per iter (compiler emits vmcnt(0)+lgkmcnt(0) there).
//   Buffer indices are compile-time 0/1 via unroll-by-2 (NITER even).
//   LDS 32->64KB: residency already ~2 blocks/CU (PV exactly 2), no loss.
//   gemm_tn deliberately untouched (3-4 blocks/CU would halve).
//   1. cvt weights fp32->bf16 (wq,bq prescaled by 1.02014 = qscale2/2^-4)
//   2. gn_stats + gn_norm -> h_t [B*P, C] bf16 (LDS tile transpose)
//   3. qk8 = h_t @ [wq;wk]^T  [B*P, 1024] fp8 e4m3
//      v_c = wv @ h_t^T       [C, B*P]  fp8 e4m3
//   4. P[b] = exp2(2^-4 * q8[b] @ k8[b]^T)  [P,P] fp8 via MX-scaled
//      mfma_scale_f32_16x16x128_f8f6f4 (A-scale e8m0=123 -> 2^-4).
//   5. h_at[b] = (P[b] @ v_c[b]^T) / (P[b] @ 1)  [P, C] bf16 (ones-MFMA
//      rowsum, fp8 1.0=0x38, layout-proof all-equal B frag).
//   6. out = wo @ h_at^T + bo + x  [C, B*P] fp32 == d_out layout
// QK/EXP/PV use bijective XCD swizzle; V/OUT keep default (already local).

typedef __bf16 bf16_t;
typedef __attribute__((ext_vector_type(4))) __bf16 bf16x4;
typedef __attribute__((ext_vector_type(8))) __bf16 bf16x8;
typedef __attribute__((ext_vector_type(4))) float floatx4;
typedef __attribute__((ext_vector_type(8))) int intx8;

constexpr int CDIM = 512;
constexpr int PDIM = 4096;

constexpr int ctz_c(int n) { return (n & 1) ? 0 : 1 + ctz_c(n >> 1); }

__device__ __forceinline__ void ld_g2l(const void* g, void* l) {
  __builtin_amdgcn_global_load_lds(
      (const __attribute__((address_space(1))) void*)g,
      (__attribute__((address_space(3))) void*)l,
      16, 0, 0);
}

__device__ __forceinline__ uint32_t pk_fp8x4(float a, float b, float c,
                                             float d) {
  int r = __builtin_amdgcn_cvt_pk_fp8_f32(a, b, 0, false);
  r = __builtin_amdgcn_cvt_pk_fp8_f32(c, d, r, true);
  return (uint32_t)r;
}

// two 16B LDS chunks -> one 8-reg MFMA fragment (SROA keeps it in regs)
__device__ __forceinline__ intx8 ld_frag(const uint8_t* base, int s0,
                                         int s1) {
  union {
    uint4 u[2];
    intx8 v;
  } r;
  r.u[0] = *(const uint4*)(base + s0);
  r.u[1] = *(const uint4*)(base + s1);
  return r.v;
}

// bijective row permutation for B staging: LDS row 16ni+fr holds global
// col 4fr+ni -> each lane's 4 ni-values are 4 consecutive columns.
__device__ __forceinline__ int sigma_row(int r) {
  return (r & 64) + ((r & 15) << 2) + ((r >> 4) & 3);
}

// bijective XCD-aware remap, compile-time pow2 grid -> pure shift/mask.
template <int GX, int GY, int GZ>
__device__ __forceinline__ void xcd_remap(int& bx, int& by, int& bz) {
  constexpr int NWG = GX * GY * GZ;
  static_assert((NWG & 7) == 0 && (GX & (GX - 1)) == 0 &&
                    (GY & (GY - 1)) == 0,
                "pow2 grid, nwg%8==0");
  int lin = bx + GX * (by + GY * bz);
  int wg = (lin & 7) * (NWG >> 3) + (lin >> 3);
  bx = wg & (GX - 1);
  int t = wg >> ctz_c(GX);
  by = t & (GY - 1);
  bz = t >> ctz_c(GY);
}

enum { EPI_QK = 0, EPI_V = 1, EPI_OUT = 4, EPI_EXP = 2, EPI_PV = 5 };

// TN GEMM (bf16): C[M,N] = A[M,K] * B[N,K]^T, TMx128 tile, BK=64, NT thr,
// 16x16x32 MFMA, sigma-staged B + packed epilogue stores. K/strides are
// compile-time; K-loop fully unrolled (8 iters).
template <int EPI, int TM, int NT, bool SWZ, int K, int LDA, int LDB,
          int LDC, int GX = 1, int GY = 1, int GZ = 1>
__global__ __launch_bounds__(NT) void gemm_tn(
    const bf16_t* __restrict__ A, const bf16_t* __restrict__ B, long sAb,
    long sBb, long sCb, void* __restrict__ Cv,
    const float* __restrict__ bias, const float* __restrict__ xres) {
  constexpr int NW = NT / 64;
  constexpr int WROWS = TM / (NW / 2);
  constexpr int MI = WROWS / 16;
  constexpr int RB = NT / 8;    // rows staged per batch
  constexpr int AB = TM / RB;   // A stage batches
  constexpr int BB = 128 / RB;  // B stage batches
  constexpr int PMAX = AB > BB ? AB : BB;
  __shared__ bf16_t Asm[TM * 64];
  __shared__ bf16_t Bsm[128 * 64];

  const int tid = threadIdx.x;
  const int w = tid >> 6, l = tid & 63;
  int bx = blockIdx.x, by = blockIdx.y, bz = blockIdx.z;
  if constexpr (SWZ) xcd_remap<GX, GY, GZ>(bx, by, bz);
  const int m0 = by * TM, n0 = bx * 128;

  const bf16_t* Ab = A + (long)bz * sAb + (long)m0 * LDA;
  const bf16_t* Bb = B + (long)bz * sBb + (long)n0 * LDB;

  const int r0 = 8 * w + (l >> 3);
  const int schunk = (l & 7) ^ (l >> 3);
  const bf16_t* ga = Ab + (long)r0 * LDA + schunk * 8;
  const bf16_t* gb = Bb + schunk * 8;
  bf16_t* lA = Asm + (8 * w) * 64;
  bf16_t* lB = Bsm + (8 * w) * 64;

  const int wr = w >> 1, wc = w & 1;
  const int fr = l & 15, fq = l >> 4, l7 = l & 7;

  floatx4 acc[MI][4];
  floatx4 zz = {0.f, 0.f, 0.f, 0.f};
#pragma unroll
  for (int i = 0; i < MI; i++)
#pragma unroll
    for (int j = 0; j < 4; j++) acc[i][j] = zz;

#pragma unroll 8
  for (int it = 0; it < K / 64; it++) {
    const int kb = it * 64;
#pragma unroll
    for (int p = 0; p < PMAX; p++) {
      if (p < AB) ld_g2l(ga + (long)(p * RB) * LDA + kb, lA + p * RB * 64);
      if (p < BB) {
        const int sig = sigma_row(r0 + RB * p);  // B rows sigma-permuted
        ld_g2l(gb + (long)sig * LDB + kb, lB + p * RB * 64);
      }
    }
    __syncthreads();
#pragma unroll
    for (int ks = 0; ks < 2; ks++) {
      bf16x8 af[MI], bfv[4];
      const int ch = (ks * 4 + fq);
#pragma unroll
      for (int mi = 0; mi < MI; mi++) {
        int row = wr * WROWS + mi * 16 + fr;
        af[mi] = *(const bf16x8*)(Asm + row * 64 + ((ch ^ l7) * 8));
      }
#pragma unroll
      for (int ni = 0; ni < 4; ni++) {
        int row = wc * 64 + ni * 16 + fr;  // row&7 == l7
        bfv[ni] = *(const bf16x8*)(Bsm + row * 64 + ((ch ^ l7) * 8));
      }
#pragma unroll
      for (int mi = 0; mi < MI; mi++)
#pragma unroll
        for (int ni = 0; ni < 4; ni++)
          acc[mi][ni] = __builtin_amdgcn_mfma_f32_16x16x32_bf16(
              af[mi], bfv[ni], acc[mi][ni], 0, 0, 0);
    }
    __syncthreads();
  }

  // epilogue: sigma staging => MFMA ni, lane fr holds global col 4fr+ni
  const int rb = fq * 4;
  const int gcolb = n0 + wc * 64 + 4 * fr;
#pragma unroll
  for (int mi = 0; mi < MI; mi++) {
#pragma unroll
    for (int i = 0; i < 4; i++) {
      const int grow = m0 + wr * WROWS + mi * 16 + rb + i;
      float v0 = acc[mi][0][i], v1 = acc[mi][1][i];
      float v2 = acc[mi][2][i], v3 = acc[mi][3][i];
      if constexpr (EPI == EPI_QK) {
        // fp8 q||k output (q side pre-scaled via weights)
        const float4 b4 = *(const float4*)(bias + gcolb);
        *(uint32_t*)((uint8_t*)Cv + (long)bz * sCb + (long)grow * LDC +
                     gcolb) =
            pk_fp8x4(v0 + b4.x, v1 + b4.y, v2 + b4.z, v3 + b4.w);
      } else if constexpr (EPI == EPI_V) {
        const float bb = bias[grow];
        uint32_t d = pk_fp8x4(v0 + bb, v1 + bb, v2 + bb, v3 + bb);
        *(uint32_t*)((uint8_t*)Cv + (long)bz * sCb + (long)grow * LDC +
                     gcolb) = d;
      } else {  // EPI_OUT: grow = out channel, gcolb = b*P+p (4-aligned)
        int ob = gcolb >> 12, op = gcolb & 4095;
        long o = ((long)ob * CDIM + grow) * PDIM + op;
        const float4 xr = *(const float4*)(xres + o);
        const float bb = bias[grow];
        float4 ov = {v0 + bb + xr.x, v1 + bb + xr.y, v2 + bb + xr.z,
                     v3 + bb + xr.w};
        *(float4*)((float*)Cv + o) = ov;
      }
    }
  }
}

// fp8 TN GEMM via MX-scaled MFMA: C[M,N] op( A[M,K] * B[N,K]^T * 2^(SA-127) )
// TMx128 tile, BK=128, NT thr, mfma_scale_f32_16x16x128_f8f6f4.
// EPI_EXP: C = fp8(exp2(acc)). EPI_PV: C = bf16(acc / (P@1)) via ones-MFMA.
// T3 2-phase LDS double-buffer: stage next tile BEFORE computing current,
// one barrier per iter; ping-pong via unroll-by-2 (static buf indices).
template <int EPI, int TM, int SA, int NT, int K, int LDA, int LDB, int LDC,
          int GX, int GY, int GZ>
__global__ __launch_bounds__(NT) void gemm_f8(
    const uint8_t* __restrict__ A, const uint8_t* __restrict__ B, long sAb,
    long sBb, long sCb, void* __restrict__ Cv) {
  constexpr int NW = NT / 64;
  constexpr int WROWS = TM / (NW / 2);
  constexpr int MI = WROWS / 16;
  constexpr int RB = NT / 8;
  constexpr int AB = TM / RB;
  constexpr int BB = 128 / RB;
  constexpr int PMAX = AB > BB ? AB : BB;
  constexpr int NITER = K / 128;
  static_assert((NITER & 1) == 0, "ping-pong needs even iter count");
  __shared__ uint8_t Asm[2][TM * 128];
  __shared__ uint8_t Bsm[2][128 * 128];

  const int tid = threadIdx.x;
  const int w = tid >> 6, l = tid & 63;
  int bx = blockIdx.x, by = blockIdx.y, bz = blockIdx.z;
  xcd_remap<GX, GY, GZ>(bx, by, bz);
  const int m0 = by * TM, n0 = bx * 128;

  const uint8_t* Ab = A + (long)bz * sAb + (long)m0 * LDA;
  const uint8_t* Bb = B + (long)bz * sBb + (long)n0 * LDB;

  const int r0 = 8 * w + (l >> 3);
  const int schunk = (l & 7) ^ (l >> 3);
  const uint8_t* ga = Ab + (long)r0 * LDA + schunk * 16;
  const uint8_t* gb = Bb + schunk * 16;
  const int lofs = (8 * w) * 128;

  const int wr = w >> 1, wc = w & 1;
  const int fr = l & 15, fq = l >> 4, l7 = l & 7;

  floatx4 acc[MI][4];
  floatx4 accr[MI];  // PV row sums (P @ ones)
#pragma unroll
  for (int i = 0; i < MI; i++) {
#pragma unroll
    for (int j = 0; j < 4; j++) acc[i][j] = floatx4{0.f, 0.f, 0.f, 0.f};
    accr[i] = floatx4{0.f, 0.f, 0.f, 0.f};
  }

  const int s0 = ((2 * fq) ^ l7) * 16;
  const int s1 = ((2 * fq + 1) ^ l7) * 16;

  // issue the 8 global_load_lds for K-tile kb into buffer buf
  auto stage = [&](int buf, int kb) {
#pragma unroll
    for (int p = 0; p < PMAX; p++) {
      if (p < AB)
        ld_g2l(ga + (long)(p * RB) * LDA + kb, &Asm[buf][lofs + p * RB * 128]);
      if (p < BB) {
        const int sig = sigma_row(r0 + RB * p);  // B rows sigma-permuted
        ld_g2l(gb + (long)sig * LDB + kb, &Bsm[buf][lofs + p * RB * 128]);
      }
    }
  };
  // ds_read fragments from buffer buf and run the MFMA cluster
  auto compute = [&](int buf) {
    intx8 af[MI];
#pragma unroll
    for (int mi = 0; mi < MI; mi++)
      af[mi] =
          ld_frag(&Asm[buf][(wr * WROWS + mi * 16 + fr) * 128], s0, s1);
#pragma unroll
    for (int ni = 0; ni < 4; ni++) {
      // row&7 == l7 -> conflict-free
      intx8 bf = ld_frag(&Bsm[buf][(wc * 64 + ni * 16 + fr) * 128], s0, s1);
#pragma unroll
      for (int mi = 0; mi < MI; mi++)
        acc[mi][ni] = __builtin_amdgcn_mfma_scale_f32_16x16x128_f8f6f4(
            af[mi], bf, acc[mi][ni], 0, 0, 0, SA, 0, 127);
    }
    if constexpr (EPI == EPI_PV) {
      const int one8 = 0x38383838;  // 4x fp8 e4m3 1.0
      const intx8 ones = {one8, one8, one8, one8, one8, one8, one8, one8};
#pragma unroll
      for (int mi = 0; mi < MI; mi++)
        accr[mi] = __builtin_amdgcn_mfma_scale_f32_16x16x128_f8f6f4(
            af[mi], ones, accr[mi], 0, 0, 0, SA, 0, 127);
    }
  };

  stage(0, 0);
  __syncthreads();  // vmcnt(0) drain of prologue stage
#pragma unroll 1
  for (int it = 0; it < NITER; it += 2) {
    stage(1, (it + 1) * 128);  // issue next tile, then compute under it
    compute(0);
    __syncthreads();  // drains: this wave's stage vmcnt + all ds_reads of buf0
    if (it + 2 < NITER) stage(0, (it + 2) * 128);
    compute(1);
    __syncthreads();
  }

  const int rb = fq * 4;
  const int gcolb = n0 + wc * 64 + 4 * fr;
#pragma unroll
  for (int mi = 0; mi < MI; mi++) {
#pragma unroll
    for (int i = 0; i < 4; i++) {
      const int grow = m0 + wr * WROWS + mi * 16 + rb + i;
      if constexpr (EPI == EPI_EXP) {
        // acc already in log2 units (weight prescale + 2^-4 MX scale)
        float p0 = exp2f(acc[mi][0][i]), p1 = exp2f(acc[mi][1][i]);
        float p2 = exp2f(acc[mi][2][i]), p3 = exp2f(acc[mi][3][i]);
        *(uint32_t*)((uint8_t*)Cv + (long)bz * sCb + (long)grow * LDC +
                     gcolb) = pk_fp8x4(p0, p1, p2, p3);
      } else {  // EPI_PV: every column of accr == rowsum for this row
        const float inv = __builtin_amdgcn_rcpf(accr[mi][i]);
        bf16x4 o = {(bf16_t)(acc[mi][0][i] * inv),
                    (bf16_t)(acc[mi][1][i] * inv),
                    (bf16_t)(acc[mi][2][i] * inv),
                    (bf16_t)(acc[mi][3][i] * inv)};
        *(bf16x4*)((bf16_t*)Cv + (long)bz * sCb + (long)grow * LDC + gcolb) =
            o;
      }
    }
  }
}

// Stage 1: partial sums. Block i reads x[i*8192 .. +8192), writes (sum, sumsq).
__global__ __launch_bounds__(256) void gn_stats(const float* __restrict__ x,
                                                float2* __restrict__ part) {
  const int i = blockIdx.x;
  const float4* xp = (const float4*)(x + (long)i * 8192);
  float s0 = 0.f, s1 = 0.f;
  for (int j = threadIdx.x; j < 2048; j += 256) {
    float4 v = xp[j];
    s0 += v.x + v.y + v.z + v.w;
    s1 += v.x * v.x + v.y * v.y + v.z * v.z + v.w * v.w;
  }
  for (int o = 32; o; o >>= 1) {
    s0 += __shfl_xor(s0, o);
    s1 += __shfl_xor(s1, o);
  }
  __shared__ float r0[4], r1[4];
  if ((threadIdx.x & 63) == 0) {
    r0[threadIdx.x >> 6] = s0;
    r1[threadIdx.x >> 6] = s1;
  }
  __syncthreads();
  if (threadIdx.x == 0)
    part[i] = make_float2(r0[0] + r0[1] + r0[2] + r0[3],
                          r1[0] + r1[1] + r1[2] + r1[3]);
}

// Stage 2: normalize + transpose via LDS tile. Block = (b, 32 p-rows).
__global__ __launch_bounds__(256) void gn_norm(
    const float* __restrict__ x, const float* __restrict__ gamma,
    const float* __restrict__ beta, const float2* __restrict__ part,
    bf16_t* __restrict__ h_t) {
  const int b = blockIdx.x >> 7;
  const int p0 = (blockIdx.x & 127) * 32;
  const int t = threadIdx.x;
  __shared__ float gmS[512], btS[512];
  __shared__ float gmean[32], grstd[32];
  __shared__ __align__(16) bf16_t tile[32 * 520];

  if (t < 32) {
    const float2* pp = part + (b * 32 + t) * 8;
    float s0 = 0.f, s1 = 0.f;
#pragma unroll
    for (int s = 0; s < 8; s++) {
      float2 v = pp[s];
      s0 += v.x;
      s1 += v.y;
    }
    float mean = s0 * (1.f / 65536.f);
    float var = s1 * (1.f / 65536.f) - mean * mean;
    gmean[t] = mean;
    grstd[t] = rsqrtf(var + 1e-6f);
  }
  __syncthreads();
  for (int c = t; c < 512; c += 256) {
    float g = gamma[c] * grstd[c >> 4];
    gmS[c] = g;
    btS[c] = beta[c] - gmean[c >> 4] * g;
  }
  __syncthreads();

  const int cc = t >> 3, pcol = (t & 7) * 4;
  for (int pass = 0; pass < 16; pass++) {
    int c = pass * 32 + cc;
    float4 v = *(const float4*)(x + ((long)(b * 512 + c)) * 4096 + p0 + pcol);
    float g = gmS[c], bb = btS[c];
    tile[(pcol + 0) * 520 + c] = (bf16_t)(v.x * g + bb);
    tile[(pcol + 1) * 520 + c] = (bf16_t)(v.y * g + bb);
    tile[(pcol + 2) * 520 + c] = (bf16_t)(v.z * g + bb);
    tile[(pcol + 3) * 520 + c] = (bf16_t)(v.w * g + bb);
  }
  __syncthreads();
  const int p = t >> 3;
  bf16_t* orow = h_t + ((long)(b * 4096 + p0 + p)) * 512;
  const bf16_t* trow = tile + p * 520;
#pragma unroll
  for (int j = 0; j < 8; j++) {
    int ch = (t & 7) + 8 * j;
    *(uint4*)(orow + ch * 8) = *(const uint4*)(trow + ch * 8);
  }
}

// wq,bq prescaled by (log2e/sqrt(512)) / 2^-4 so the EXP GEMM's e8m0
// A-scale of 123 (2^-4) yields log2-domain scores directly.
__global__ __launch_bounds__(256) void cvt_weights(
    const float* __restrict__ wq, const float* __restrict__ wk,
    const float* __restrict__ wv, const float* __restrict__ wo,
    const float* __restrict__ bq, const float* __restrict__ bk,
    bf16_t* __restrict__ out, float* __restrict__ bqk) {
  constexpr float QW = 1.02013936f;  // (1/sqrt(512))*log2(e) / 2^-4
  int i = blockIdx.x * 256 + threadIdx.x;
  out[i] = (bf16_t)(wq[i] * QW);
  out[262144 + i] = (bf16_t)wk[i];
  out[2 * 262144 + i] = (bf16_t)wv[i];
  out[3 * 262144 + i] = (bf16_t)wo[i];
  if (i < 512)
    bqk[i] = bq[i] * QW;
  else if (i < 1024)
    bqk[i] = bk[i - 512];
}

extern "C" void kernel_launch(void* const* d_in, const int* in_sizes, int n_in,
                              void* d_out, int out_size, void* d_ws,
                              size_t ws_size, hipStream_t stream) {
  const float* x = (const float*)d_in[0];
  const float* gamma = (const float*)d_in[1];
  const float* beta = (const float*)d_in[2];
  const float* wq = (const float*)d_in[3];
  const float* bq = (const float*)d_in[4];
  const float* wk = (const float*)d_in[5];
  const float* bk = (const float*)d_in[6];
  const float* wv = (const float*)d_in[7];
  const float* bv = (const float*)d_in[8];
  const float* wo = (const float*)d_in[9];
  const float* bo = (const float*)d_in[10];

  char* ws = (char*)d_ws;
  bf16_t* h_t = (bf16_t*)(ws);                  // [16384,512] bf16  @0
  uint8_t* qk8 = (uint8_t*)(ws + (16l << 20));  // [16384,1024] fp8  @16MB
  uint8_t* v_c = (uint8_t*)(ws + (48l << 20));  // [512,16384] fp8   @48MB
  bf16_t* h_at = (bf16_t*)(ws + (64l << 20));   // [16384,512] bf16  @64MB
  bf16_t* w_b = (bf16_t*)(ws + (80l << 20));    // 4x[512,512] bf16  @80MB
  float2* part = (float2*)(ws + (83l << 20));   // [1024] partials   @83MB
  float* bqk = (float*)(ws + (83l << 20) + (64l << 10));  // [1024]
  uint8_t* Sbuf = (uint8_t*)(ws + (84l << 20)); // [4,4096,4096] fp8 @84MB

  const long sQK8 = (long)PDIM * 1024;  // bytes per batch of qk8
  const long sS = (long)PDIM * PDIM;    // 16777216

  cvt_weights<<<1024, 256, 0, stream>>>(wq, wk, wv, wo, bq, bk, w_b, bqk);
  gn_stats<<<1024, 256, 0, stream>>>(x, part);
  gn_norm<<<512, 256, 0, stream>>>(x, gamma, beta, part, h_t);
  // fused q|k projection -> fp8: B = [wq;wk] rows 0..1023, bias bqk
  gemm_tn<EPI_QK, 128, 256, true, 512, 512, 512, 1024, 8, 128, 1>
      <<<dim3(8, 128, 1), 256, 0, stream>>>(h_t, w_b, 0, 0, 0, qk8, bqk,
                                            nullptr);
  gemm_tn<EPI_V, 64, 256, false, 512, 512, 512, 16384>
      <<<dim3(128, 8, 1), 256, 0, stream>>>(w_b + 2 * 262144, h_t, 0, 0, 0,
                                            v_c, bv, nullptr);
  // P = exp2(2^-4 * q8 k8^T) fp8 (unnormalized; sums computed in PV)
  gemm_f8<EPI_EXP, 128, 123, 256, 512, 1024, 1024, 4096, 32, 32, 4>
      <<<dim3(32, 32, 4), 256, 0, stream>>>(qk8, qk8 + 512, sQK8, sQK8, sS,
                                            Sbuf);
  // h_at = (P @ v^T) / (P @ 1)  — MX-fp8 K=128 MFMA, rsum via ones-MFMA
  gemm_f8<EPI_PV, 128, 127, 256, 4096, 4096, 16384, 512, 4, 32, 4>
      <<<dim3(4, 32, 4), 256, 0, stream>>>(Sbuf, v_c, sS, 4096,
                                           (long)PDIM * CDIM, h_at);
  gemm_tn<EPI_OUT, 64, 256, false, 512, 512, 512, 4096>
      <<<dim3(128, 8, 1), 256, 0, stream>>>(w_b + 3 * 262144, h_at, 0, 0, 0,
                                            d_out, bo, x);
}